// Round 7
// baseline (17256.822 us; speedup 1.0000x reference)
//
#include <hip/hip_runtime.h>
#include <math.h>

// Problem constants
#define NTOT   8192
#define BGR    128
#define NPER   64
#define EDIR   65536
#define EKEEP  32768
#define EPSC   1e-5f

typedef unsigned short ushortT;

// Operand dtype codes: 0 = bf16, 1 = f32, 2 = runtime (read *flagp)
#define C_BF 0
#define C_F32 1
#define C_RT 2

// ---------------- dtype helpers ----------------
__device__ __forceinline__ float bf2f(ushortT u) {
    union { unsigned int i; float f; } v; v.i = ((unsigned int)u) << 16; return v.f;
}
__device__ __forceinline__ ushortT f2bf(float f) {
    unsigned int u = __float_as_uint(f);
    u += 0x7FFFu + ((u >> 16) & 1u);   // round to nearest even
    return (ushortT)(u >> 16);
}
__device__ __forceinline__ float get1(const void* p, long i, int f) {
    return f ? ((const float*)p)[i] : bf2f(((const ushortT*)p)[i]);
}
__device__ __forceinline__ float4 get4(const void* p, long i, int f) {
    if (f) return *(const float4*)((const float*)p + i);
    ushort4 u = *(const ushort4*)((const ushortT*)p + i);
    return make_float4(bf2f(u.x), bf2f(u.y), bf2f(u.z), bf2f(u.w));
}
__device__ __forceinline__ float4 ld4(const ushortT* p) {
    ushort4 u = *(const ushort4*)p;
    return make_float4(bf2f(u.x), bf2f(u.y), bf2f(u.z), bf2f(u.w));
}
__device__ __forceinline__ float4 ld4(const float* p) { return *(const float4*)p; }
__device__ __forceinline__ void st4(float* p, float4 v) { *(float4*)p = v; }
__device__ __forceinline__ void st4(ushortT* p, float4 v) {
    ushort4 u; u.x = f2bf(v.x); u.y = f2bf(v.y); u.z = f2bf(v.z); u.w = f2bf(v.w);
    *(ushort4*)p = u;
}
__device__ __forceinline__ int clampi(int v, int lo, int hi) {
    return v < lo ? lo : (v > hi ? hi : v);
}

// ---------------------------------------------------------------------------
// Float-input dtype detector. If x is bf16, the LOW 16 bits of each 32-bit
// word are a bf16 ~N(0,1) value whose exponent field lies in a narrow band.
// If x is f32, low 16 bits are mantissa noise (uniform exponent field).
// flag = 1 (f32) iff band-hits are rare.
// ---------------------------------------------------------------------------
__launch_bounds__(256)
__global__ void detect_k(const unsigned int* __restrict__ xw, int* __restrict__ flag)
{
    __shared__ int red[256];
    const int t = threadIdx.x;
    int hits = 0;
#pragma unroll
    for (int i = 0; i < 4; ++i) {
        const unsigned w = xw[t*4 + i];
        const unsigned eb = (w >> 7) & 0xFF;   // exponent field of low-half bf16
        hits += (eb >= 100 && eb <= 150) ? 1 : 0;
    }
    red[t] = hits; __syncthreads();
#pragma unroll
    for (int s = 128; s > 0; s >>= 1) { if (t < s) red[t] += red[t+s]; __syncthreads(); }
    if (t == 0) *flag = (red[0] < 512) ? 1 : 0;
}

// ---------------------------------------------------------------------------
// Generic tiled GEMM: C = alpha*(A @ B[^T]) (+bias) (+C) (relu?)
// 64x64 tile, BK=16, 256 threads, 4x4/thread, fp32 accumulate.
// A/B/bias dtypes resolved at runtime via codes (C_BF/C_F32/C_RT).
// ---------------------------------------------------------------------------
template<class TC, bool BT, bool BIAS, bool RELU, bool RESID>
__launch_bounds__(256)
__global__ void gemm_k(const void* __restrict__ A, int cA,
                       const void* __restrict__ B, int cB,
                       const void* __restrict__ bias, int cBias,
                       TC* __restrict__ C, const int* __restrict__ flagp,
                       int K, int lda, int ldb, int ldc,
                       long sA, long sB, long sC, float alpha)
{
    const int rtf = *flagp;
    const int fA = (cA == C_RT) ? rtf : cA;
    const int fB = (cB == C_RT) ? rtf : cB;

    const int t  = threadIdx.x;
    const int tx = t & 15, ty = t >> 4;
    const int m0 = blockIdx.y * 64, n0 = blockIdx.x * 64;
    const long z = blockIdx.z;
    const long aOff = z * sA, bOff = z * sB, cOff = z * sC;

    __shared__ float As[16][65];
    __shared__ float Bs[16][64];

    const int a_m = t >> 2, a_k = (t & 3) << 2;   // A: 64 rows x 16 k
    const int b_k = t >> 4, b_n = (t & 15) << 2;  // B (no-T): 16 k x 64 n

    float acc[4][4] = {};

    for (int k0 = 0; k0 < K; k0 += 16) {
        float4 av = get4(A, aOff + (long)(m0 + a_m) * lda + (k0 + a_k), fA);
        As[a_k + 0][a_m] = av.x;
        As[a_k + 1][a_m] = av.y;
        As[a_k + 2][a_m] = av.z;
        As[a_k + 3][a_m] = av.w;
        if constexpr (!BT) {
            float4 bv = get4(B, bOff + (long)(k0 + b_k) * ldb + (n0 + b_n), fB);
            *(float4*)(&Bs[b_k][b_n]) = bv;
        } else {
            float4 bv = get4(B, bOff + (long)(n0 + a_m) * ldb + (k0 + a_k), fB);
            Bs[a_k + 0][a_m] = bv.x;
            Bs[a_k + 1][a_m] = bv.y;
            Bs[a_k + 2][a_m] = bv.z;
            Bs[a_k + 3][a_m] = bv.w;
        }
        __syncthreads();
#pragma unroll
        for (int kk = 0; kk < 16; ++kk) {
            const float a0 = As[kk][ty*4+0], a1 = As[kk][ty*4+1];
            const float a2 = As[kk][ty*4+2], a3 = As[kk][ty*4+3];
            const float4 bv = *(const float4*)(&Bs[kk][tx*4]);
            acc[0][0] += a0*bv.x; acc[0][1] += a0*bv.y; acc[0][2] += a0*bv.z; acc[0][3] += a0*bv.w;
            acc[1][0] += a1*bv.x; acc[1][1] += a1*bv.y; acc[1][2] += a1*bv.z; acc[1][3] += a1*bv.w;
            acc[2][0] += a2*bv.x; acc[2][1] += a2*bv.y; acc[2][2] += a2*bv.z; acc[2][3] += a2*bv.w;
            acc[3][0] += a3*bv.x; acc[3][1] += a3*bv.y; acc[3][2] += a3*bv.z; acc[3][3] += a3*bv.w;
        }
        __syncthreads();
    }

    float4 bgl = make_float4(0.f, 0.f, 0.f, 0.f);
    if constexpr (BIAS) {
        const int fBb = (cBias == C_RT) ? rtf : cBias;
        bgl = get4(bias, n0 + tx*4, fBb);
    }
#pragma unroll
    for (int i = 0; i < 4; ++i) {
        const int m = m0 + ty*4 + i;
        TC* cp = C + cOff + (long)m * ldc + (n0 + tx*4);
        float4 r;
        r.x = alpha*acc[i][0] + bgl.x;
        r.y = alpha*acc[i][1] + bgl.y;
        r.z = alpha*acc[i][2] + bgl.z;
        r.w = alpha*acc[i][3] + bgl.w;
        if constexpr (RESID) {
            float4 c0 = ld4(cp);
            r.x += c0.x; r.y += c0.y; r.z += c0.z; r.w += c0.w;
        }
        if constexpr (RELU) {
            r.x = fmaxf(r.x, 0.f); r.y = fmaxf(r.y, 0.f);
            r.z = fmaxf(r.z, 0.f); r.w = fmaxf(r.w, 0.f);
        }
        st4(cp, r);
    }
}

// ---------------- block reduction (256 threads) ----------------
__device__ __forceinline__ float blockReduceSum(float v, float* red, int t)
{
    red[t] = v; __syncthreads();
#pragma unroll
    for (int s = 128; s > 0; s >>= 1) {
        if (t < s) red[t] += red[t + s];
        __syncthreads();
    }
    const float r = red[0];
    __syncthreads();
    return r;
}

// ---------------------------------------------------------------------------
// gconv1 fused: edge-weight embedding + segment_sum + [5->256] dense + relu
// ---------------------------------------------------------------------------
__launch_bounds__(256)
__global__ void gconv1_k(int b0, const void* __restrict__ x, const int* __restrict__ edges,
                         const void* __restrict__ ea,
                         const void* __restrict__ wembW, const void* __restrict__ wembB,
                         const void* __restrict__ Wrel, const void* __restrict__ brel,
                         const void* __restrict__ Wroot, ushortT* __restrict__ h1,
                         const int* __restrict__ flagp)
{
    const int f = *flagp;
    const int bl = blockIdx.x, g = b0 + bl, t = threadIdx.x;
    __shared__ float s_x[64][5];
    __shared__ float s_agg[64][5];
    __shared__ int   s_cnt[64];
    __shared__ int   s_off[65];
    __shared__ int   s_src[512];
    __shared__ float s_w[512];

    if (t < 64) s_cnt[t] = 0;
    if (t < 320) s_x[t/5][t%5] = get1(x, (long)(g*64 + t/5)*5 + (t%5), f);
    __syncthreads();

    const float w0 = get1(wembW,0,f), w1 = get1(wembW,1,f), w2 = get1(wembW,2,f);
    const float wb = get1(wembB,0,f);
    int sl[2], dl[2], slot[2]; float wv[2];
#pragma unroll
    for (int e2 = 0; e2 < 2; ++e2) {
        const int e = g*512 + t + 256*e2;
        const int s = edges[e], d = edges[EDIR + e];
        sl[e2] = clampi(s - g*64, 0, 63); dl[e2] = clampi(d - g*64, 0, 63);
        const float a0 = get1(ea, 2L*e, f), a1 = get1(ea, 2L*e+1, f);
        wv[e2] = fmaxf(a0*w0 + ((a1 < 0.5f) ? w1 : w2) + wb, 0.f);
        slot[e2] = atomicAdd(&s_cnt[dl[e2]], 1);
    }
    __syncthreads();
    if (t == 0) {
        int r = 0;
        for (int i = 0; i < 64; ++i) { s_off[i] = r; r += s_cnt[i]; }
        s_off[64] = r;
    }
    __syncthreads();
#pragma unroll
    for (int e2 = 0; e2 < 2; ++e2) {
        const int p = s_off[dl[e2]] + slot[e2];
        s_src[p] = sl[e2]; s_w[p] = wv[e2];
    }
    __syncthreads();
    if (t < 320) {
        const int n = t/5, k = t%5;
        float acc = 0.f;
        for (int i = s_off[n]; i < s_off[n+1]; ++i) acc += s_w[i] * s_x[s_src[i]][k];
        s_agg[n][k] = acc;
    }
    __syncthreads();
    float wr[5], wo[5];
#pragma unroll
    for (int k = 0; k < 5; ++k) { wr[k] = get1(Wrel, k*256 + t, f); wo[k] = get1(Wroot, k*256 + t, f); }
    const float bb = get1(brel, t, f);
    for (int n = 0; n < 64; ++n) {
        float v = bb;
#pragma unroll
        for (int k = 0; k < 5; ++k) v += s_agg[n][k]*wr[k] + s_x[n][k]*wo[k];
        h1[(bl*64 + n)*256 + t] = f2bf(fmaxf(v, 0.f));
    }
}

// ---------------------------------------------------------------------------
// gconv2 aggregation: agg2 = segment_sum(w * h1[src], dst).
// ---------------------------------------------------------------------------
__launch_bounds__(256)
__global__ void gconv2_agg_k(int b0, const ushortT* __restrict__ h1, const int* __restrict__ edges,
                             const void* __restrict__ ea,
                             const void* __restrict__ wembW, const void* __restrict__ wembB,
                             ushortT* __restrict__ agg2, const int* __restrict__ flagp)
{
    const int f = *flagp;
    const int bl = blockIdx.x, g = b0 + bl, t = threadIdx.x;
    __shared__ int   s_cnt[64];
    __shared__ int   s_off[65];
    __shared__ int   s_src[512];
    __shared__ float s_w[512];

    if (t < 64) s_cnt[t] = 0;
    __syncthreads();

    const float w0 = get1(wembW,0,f), w1 = get1(wembW,1,f), w2 = get1(wembW,2,f);
    const float wb = get1(wembB,0,f);
    int sl[2], dl[2], slot[2]; float wv[2];
#pragma unroll
    for (int e2 = 0; e2 < 2; ++e2) {
        const int e = g*512 + t + 256*e2;
        const int s = edges[e], d = edges[EDIR + e];
        sl[e2] = clampi(s - g*64, 0, 63); dl[e2] = clampi(d - g*64, 0, 63);
        const float a0 = get1(ea, 2L*e, f), a1 = get1(ea, 2L*e+1, f);
        wv[e2] = fmaxf(a0*w0 + ((a1 < 0.5f) ? w1 : w2) + wb, 0.f);
        slot[e2] = atomicAdd(&s_cnt[dl[e2]], 1);
    }
    __syncthreads();
    if (t == 0) {
        int r = 0;
        for (int i = 0; i < 64; ++i) { s_off[i] = r; r += s_cnt[i]; }
        s_off[64] = r;
    }
    __syncthreads();
#pragma unroll
    for (int e2 = 0; e2 < 2; ++e2) {
        const int p = s_off[dl[e2]] + slot[e2];
        s_src[p] = sl[e2]; s_w[p] = wv[e2];
    }
    __syncthreads();
    for (int n = 0; n < 64; ++n) {
        float acc = 0.f;
        const int i0 = s_off[n], i1 = s_off[n+1];
        for (int i = i0; i < i1; ++i)
            acc += s_w[i] * bf2f(h1[(bl*64 + s_src[i])*256 + t]);
        agg2[(bl*64 + n)*256 + t] = f2bf(acc);
    }
}

// ---------------------------------------------------------------------------
// GraphNorm, chunk-local h (64 nodes/block, 512 features, in place, bf16).
// ---------------------------------------------------------------------------
__launch_bounds__(256)
__global__ void gnorm_k(ushortT* __restrict__ h, const void* __restrict__ gw,
                        const void* __restrict__ gb, const void* __restrict__ gms,
                        const int* __restrict__ flagp)
{
    const int f0 = *flagp;
    const int bl = blockIdx.x, t = threadIdx.x;
#pragma unroll
    for (int f2 = 0; f2 < 2; ++f2) {
        const int f = t + 256*f2;
        float acc = 0.f;
        for (int n = 0; n < 64; ++n) acc += bf2f(h[(bl*64+n)*512 + f]);
        const float m2 = get1(gms, f, f0) * (acc * (1.f/64.f));
        float v = 0.f;
        for (int n = 0; n < 64; ++n) { const float d = bf2f(h[(bl*64+n)*512 + f]) - m2; v += d*d; }
        const float rs = rsqrtf(v*(1.f/64.f) + EPSC);
        const float g = get1(gw, f, f0), bb = get1(gb, f, f0);
        for (int n = 0; n < 64; ++n) {
            const int idx = (bl*64+n)*512 + f;
            h[idx] = f2bf(g * (bf2f(h[idx]) - m2) * rs + bb);
        }
    }
}

// ---------------------------------------------------------------------------
// SplitSyndromes: keep src>dst, stable sort by (src,dst) within each graph.
// (Pure int path — validated by Output 0 passing.)
// ---------------------------------------------------------------------------
__launch_bounds__(256)
__global__ void sort_k(const int* __restrict__ edges, int* __restrict__ sorted_orig,
                       int* __restrict__ se, int* __restrict__ te)
{
    const int b = blockIdx.x, t = threadIdx.x;
    __shared__ int s_keep[512];
    __shared__ int s_key[512];
    __shared__ int s_ckey[256];
    __shared__ int s_corig[256];
#pragma unroll
    for (int e2 = 0; e2 < 2; ++e2) {
        const int el = t + 256*e2;
        const int e = b*512 + el;
        const int s = edges[e], d = edges[EDIR + e];
        s_keep[el] = (s > d) ? 1 : 0;
        s_key[el]  = ((s - b*64) << 6) | (d - b*64);
    }
    __syncthreads();
#pragma unroll
    for (int e2 = 0; e2 < 2; ++e2) {
        const int el = t + 256*e2;
        if (s_keep[el]) {
            int pos = 0;
            for (int j = 0; j < el; ++j) pos += s_keep[j];
            s_ckey[pos]  = s_key[el];
            s_corig[pos] = b*512 + el;
        }
    }
    __syncthreads();
    const int ki = s_ckey[t];
    int rank = 0;
    for (int j = 0; j < 256; ++j) {
        const int kj = s_ckey[j];
        rank += (kj < ki || (kj == ki && j < t)) ? 1 : 0;
    }
    const int orig = s_corig[t];
    const int p = b*256 + rank;
    sorted_orig[p] = orig;
    se[p] = edges[orig];
    te[p] = edges[EDIR + orig];
}

// ---------------------------------------------------------------------------
// Build F_c = [h[src] | relu(edge emb) | h[dst]] (bf16), chunk-local h.
// ---------------------------------------------------------------------------
__launch_bounds__(256)
__global__ void fbuild_k(int b0, int maxn, const ushortT* __restrict__ h,
                         const int* __restrict__ sorted_orig,
                         const int* __restrict__ se, const int* __restrict__ te,
                         const void* __restrict__ ea,
                         const void* __restrict__ eW, const void* __restrict__ eB,
                         ushortT* __restrict__ F, const int* __restrict__ flagp)
{
    const int fl = *flagp;
    const int e = blockIdx.x, t = threadIdx.x;        // e local within chunk
    const int ge = b0*256 + e;                        // global kept-edge index
    const int s = clampi(se[ge] - b0*64, 0, maxn);
    const int d = clampi(te[ge] - b0*64, 0, maxn);
    const int orig = clampi(sorted_orig[ge], 0, EDIR-1);
    const float a0 = get1(ea, 2L*orig, fl), a1 = get1(ea, 2L*orig + 1, fl);
#pragma unroll
    for (int c = 0; c < 6; ++c) {
        const int col = c*256 + t;
        float v;
        if (c < 2) {
            v = bf2f(h[(long)s*512 + col]);
        } else if (c < 4) {
            const int ff = col - 512;
            v = fmaxf(a0*get1(eW, ff, fl)
                      + ((a1 < 0.5f) ? get1(eW, 512+ff, fl) : get1(eW, 1024+ff, fl))
                      + get1(eB, ff, fl), 0.f);
        } else {
            v = bf2f(h[(long)d*512 + (col - 1024)]);
        }
        F[(long)e*1536 + col] = f2bf(v);
    }
}

// ---------------- row softmax over 256 cols (f32 in place) ----------------
__launch_bounds__(256)
__global__ void softmax_k(float* __restrict__ S)
{
    const long row = blockIdx.x;
    const int t = threadIdx.x;
    __shared__ float red[256];
    const float v = S[row*256 + t];
    red[t] = v; __syncthreads();
#pragma unroll
    for (int s = 128; s > 0; s >>= 1) { if (t < s) red[t] = fmaxf(red[t], red[t+s]); __syncthreads(); }
    const float mx = red[0]; __syncthreads();
    const float e = __expf(v - mx);
    red[t] = e; __syncthreads();
#pragma unroll
    for (int s = 128; s > 0; s >>= 1) { if (t < s) red[t] += red[t+s]; __syncthreads(); }
    const float sum = red[0];
    S[row*256 + t] = e / sum;
}

// ---------------- fused LayerNorm + head dot (bf16 F) ----------------
__launch_bounds__(256)
__global__ void ln_head_k(int b0, const ushortT* __restrict__ F, const void* __restrict__ lng,
                          const void* __restrict__ lnb, const void* __restrict__ hW,
                          const void* __restrict__ hB, float* __restrict__ gout,
                          const int* __restrict__ flagp)
{
    const int fl = *flagp;
    const int e = blockIdx.x, t = threadIdx.x;
    __shared__ float red[256];
    float xv[6];
    float s = 0.f;
#pragma unroll
    for (int c = 0; c < 6; ++c) { xv[c] = bf2f(F[(long)e*1536 + c*256 + t]); s += xv[c]; }
    const float tot = blockReduceSum(s, red, t);
    const float mu = tot * (1.f/1536.f);
    float ss = 0.f;
#pragma unroll
    for (int c = 0; c < 6; ++c) { const float d = xv[c] - mu; ss += d*d; }
    const float tot2 = blockReduceSum(ss, red, t);
    const float rs = rsqrtf(tot2 * (1.f/1536.f) + EPSC);
    float p = 0.f;
#pragma unroll
    for (int c = 0; c < 6; ++c) {
        const int col = c*256 + t;
        p += (get1(lng, col, fl) * (xv[c] - mu) * rs + get1(lnb, col, fl)) * get1(hW, col, fl);
    }
    const float tot3 = blockReduceSum(p, red, t);
    if (t == 0) gout[b0*256 + e] = tot3 + get1(hB, 0, fl);
}

// ---------------- final: pair argmin + float32 output assembly --------------
__launch_bounds__(128)
__global__ void final_k(const float* __restrict__ gout, const int* __restrict__ se,
                        const int* __restrict__ te, const int* __restrict__ sorted_orig,
                        const void* __restrict__ ea, float* __restrict__ out,
                        const int* __restrict__ flagp)
{
    const int fl = *flagp;
    const int b = blockIdx.x, j = threadIdx.x;  // 128 pairs per graph
    const int e0 = b*256 + 2*j, e1 = e0 + 1;
    const float p0 = gout[e0], p1 = gout[e1];
    const int idx = (p1 < p0) ? 1 : 0;
    const float val = idx ? p1 : p0;
    const int eo = idx ? e1 : e0;
    const int orig = clampi(sorted_orig[eo], 0, EDIR-1);
    const float cls = get1(ea, 2L*orig + 1, fl);
    out[(b*128 + j)*2 + 0] = (float)se[e0];
    out[(b*128 + j)*2 + 1] = (float)te[e0];
    out[32768 + b*128 + j] = val;
    out[32768 + 16384 + b*128 + j] = cls;
}

// ---------------------------------------------------------------------------
// Launch. Weights mapped from in_sizes (robust to dropped/kept bool inputs).
// Workspace: fixed ~0.53 MB + G*4.33 MB, G adaptive (ws_size-proven >= ~37MB).
// ---------------------------------------------------------------------------
extern "C" void kernel_launch(void* const* d_in, const int* in_sizes, int n_in,
                              void* d_out, int out_size, void* d_ws, size_t ws_size,
                              hipStream_t stream)
{
    (void)out_size;

    const void* x     = d_in[0];
    const int*  edges = (const int*)d_in[1];
    const void* ea    = d_in[2];

    // Locate w_emb_W (unique element count 3) scanning from index 3; the 27
    // weight tensors follow in setup_inputs() dict order. This tolerates the
    // harness keeping or dropping detector_labels / batch_labels.
    int ws0 = 3;
    while (ws0 < n_in && in_sizes[ws0] != 3) ++ws0;
    if (ws0 + 27 > n_in) ws0 = 5;  // fallback: standard 32-input layout

    const void* wembW  = d_in[ws0 + 0];
    const void* wembB  = d_in[ws0 + 1];
    const void* g1Wrel = d_in[ws0 + 2];
    const void* g1brel = d_in[ws0 + 3];
    const void* g1Wroot= d_in[ws0 + 4];
    const void* g2Wrel = d_in[ws0 + 5];
    const void* g2brel = d_in[ws0 + 6];
    const void* g2Wroot= d_in[ws0 + 7];
    const void* gnw    = d_in[ws0 + 8];
    const void* gnb    = d_in[ws0 + 9];
    const void* gnms   = d_in[ws0 + 10];
    const void* eembW  = d_in[ws0 + 11];
    const void* eembB  = d_in[ws0 + 12];
    const void* qkvW   = d_in[ws0 + 13];
    const void* qkvb   = d_in[ws0 + 14];
    const void* inWq   = d_in[ws0 + 15];
    const void* inWk   = d_in[ws0 + 16];
    const void* inWv   = d_in[ws0 + 17];
    const void* inbq   = d_in[ws0 + 18];
    const void* inbk   = d_in[ws0 + 19];
    const void* inbv   = d_in[ws0 + 20];
    const void* outW   = d_in[ws0 + 21];
    const void* outb   = d_in[ws0 + 22];
    const void* lng    = d_in[ws0 + 23];
    const void* lnb    = d_in[ws0 + 24];
    const void* headW  = d_in[ws0 + 25];
    const void* headb  = d_in[ws0 + 26];

    char* ws = (char*)d_ws;
    size_t off = 0;
    auto alloc = [&](size_t bytes) {
        void* p = ws + off;
        off = (off + bytes + 255) & ~(size_t)255;
        return p;
    };
    // ---- fixed region ----
    int*   dflag  = (int*)  alloc(256);
    float* gout   = (float*)alloc(EKEEP*4);
    int*   sorted = (int*)  alloc(EKEEP*4);
    int*   seg    = (int*)  alloc(EKEEP*4);
    int*   teg    = (int*)  alloc(EKEEP*4);
    const size_t fixedB = off;

    const size_t perG = 64L*512*2 + 2L*64*256*2 + 5L*256*1536*2 + 256L*256*4;
    int G = 128;
    while (G > 1 && fixedB + (size_t)G*perG + 8192 > ws_size) G >>= 1;

    ushortT* h_c  = (ushortT*)alloc((size_t)G*64*512*2);
    ushortT* h1_c = (ushortT*)alloc((size_t)G*64*256*2);
    ushortT* ag_c = (ushortT*)alloc((size_t)G*64*256*2);
    ushortT* F_c  = (ushortT*)alloc((size_t)G*256*1536*2);
    ushortT* A_c  = (ushortT*)alloc((size_t)G*256*1536*2);
    ushortT* Q_c  = (ushortT*)alloc((size_t)G*256*1536*2);
    ushortT* K_c  = (ushortT*)alloc((size_t)G*256*1536*2);
    ushortT* V_c  = (ushortT*)alloc((size_t)G*256*1536*2);
    float*   S_c  = (float*)  alloc((size_t)G*256*256*4);

    const float scale = 0.02551551815399144f;  // 1/sqrt(1536)
    const dim3 blk(256);

    // ---- dtype detection + global edge select/sort ----
    detect_k<<<1, blk, 0, stream>>>((const unsigned int*)x, dflag);
    sort_k<<<128, blk, 0, stream>>>(edges, sorted, seg, teg);

    // ---- per-chunk full pipeline (G graphs per chunk) ----
    const int nchunk = 128 / G;
    const int EC = G * 256;
    for (int c = 0; c < nchunk; ++c) {
        const int b0 = c * G;
        gconv1_k<<<G, blk, 0, stream>>>(b0, x, edges, ea, wembW, wembB,
                                        g1Wrel, g1brel, g1Wroot, h1_c, dflag);
        gconv2_agg_k<<<G, blk, 0, stream>>>(b0, h1_c, edges, ea, wembW, wembB, ag_c, dflag);
        gemm_k<ushortT,false,true,false,false><<<dim3(8,G,1), blk, 0, stream>>>(
            h1_c, C_BF, g2Wrel, C_RT, g2brel, C_RT, h_c, dflag,
            256, 256, 512, 512, 0,0,0, 0.f);
        // note: first gemm writes agg2 @ Wrel + brel; redo with correct A:
        gemm_k<ushortT,false,true,false,false><<<dim3(8,G,1), blk, 0, stream>>>(
            ag_c, C_BF, g2Wrel, C_RT, g2brel, C_RT, h_c, dflag,
            256, 256, 512, 512, 0,0,0, 1.f);
        gemm_k<ushortT,false,false,true,true><<<dim3(8,G,1), blk, 0, stream>>>(
            h1_c, C_BF, g2Wroot, C_RT, (const void*)nullptr, C_BF, h_c, dflag,
            256, 256, 512, 512, 0,0,0, 1.f);
        gnorm_k<<<G, blk, 0, stream>>>(h_c, gnw, gnb, gnms, dflag);
        fbuild_k<<<EC, blk, 0, stream>>>(b0, G*64-1, h_c, sorted, seg, teg, ea,
                                         eembW, eembB, F_c, dflag);
        // Q path
        gemm_k<ushortT,false,true,false,false><<<dim3(24,G*4,1), blk, 0, stream>>>(
            F_c, C_BF, qkvW, C_RT, qkvb, C_RT, A_c, dflag,
            1536, 1536, 4608, 1536, 0,0,0, 1.f);
        gemm_k<ushortT,false,true,false,false><<<dim3(24,G*4,1), blk, 0, stream>>>(
            A_c, C_BF, inWq, C_RT, inbq, C_RT, Q_c, dflag,
            1536, 1536, 1536, 1536, 0,0,0, 1.f);
        // K path (column offset 1536 into qkvW/qkvb handled via element offset)
        gemm_k<ushortT,false,true,false,false><<<dim3(24,G*4,1), blk, 0, stream>>>(
            F_c, C_BF, qkvW, C_RT, qkvb, C_RT, A_c, dflag,
            1536, 1536, 4608, 1536, 0, 1536, 0, 1.f);
        gemm_k<ushortT,false,true,false,false><<<dim3(24,G*4,1), blk, 0, stream>>>(
            A_c, C_BF, inWk, C_RT, inbk, C_RT, K_c, dflag,
            1536, 1536, 1536, 1536, 0,0,0, 1.f);
        // V path
        gemm_k<ushortT,false,true,false,false><<<dim3(24,G*4,1), blk, 0, stream>>>(
            F_c, C_BF, qkvW, C_RT, qkvb, C_RT, A_c, dflag,
            1536, 1536, 4608, 1536, 0, 3072, 0, 1.f);
        gemm_k<ushortT,false,true,false,false><<<dim3(24,G*4,1), blk, 0, stream>>>(
            A_c, C_BF, inWv, C_RT, inbv, C_RT, V_c, dflag,
            1536, 1536, 1536, 1536, 0,0,0, 1.f);
        // S_b = scale * Q_b @ K_b^T (per-graph batch)
        gemm_k<float,true,false,false,false><<<dim3(4,4,G), blk, 0, stream>>>(
            Q_c, C_BF, K_c, C_BF, (const void*)nullptr, C_BF, S_c, dflag,
            1536, 1536, 1536, 256, 256L*1536, 256L*1536, 65536L, scale);
        softmax_k<<<EC, blk, 0, stream>>>(S_c);
        // R_b = P_b @ V_b -> A_c
        gemm_k<ushortT,false,false,false,false><<<dim3(24,4,G), blk, 0, stream>>>(
            S_c, C_F32, V_c, C_BF, (const void*)nullptr, C_BF, A_c, dflag,
            256, 256, 1536, 1536, 65536L, 256L*1536, 256L*1536, 1.f);
        // F += R @ out_W + out_b (residual)
        gemm_k<ushortT,false,true,false,true><<<dim3(24,G*4,1), blk, 0, stream>>>(
            A_c, C_BF, outW, C_RT, outb, C_RT, F_c, dflag,
            1536, 1536, 1536, 1536, 0,0,0, 1.f);
        ln_head_k<<<EC, blk, 0, stream>>>(b0, F_c, lng, lnb, headW, headb, gout, dflag);
    }

    final_k<<<128, dim3(128), 0, stream>>>(gout, seg, teg, sorted, ea, (float*)d_out, dflag);
}

// Round 8
// 6597.501 us; speedup vs baseline: 2.6157x; 2.6157x over previous
//
#include <hip/hip_runtime.h>
#include <math.h>

// Problem constants
#define NTOT   8192
#define BGR    128
#define NPER   64
#define EDIR   65536
#define EKEEP  32768
#define EPSC   1e-5f

typedef unsigned short ushortT;
typedef __attribute__((ext_vector_type(8))) short bf16x8;
typedef __attribute__((ext_vector_type(4))) float f32x4;

// Operand dtype codes: 0 = bf16, 1 = f32, 2 = runtime (read *flagp)
#define C_BF 0
#define C_F32 1
#define C_RT 2

// ---------------- dtype helpers ----------------
__device__ __forceinline__ float bf2f(ushortT u) {
    union { unsigned int i; float f; } v; v.i = ((unsigned int)u) << 16; return v.f;
}
__device__ __forceinline__ ushortT f2bf(float f) {
    unsigned int u = __float_as_uint(f);
    u += 0x7FFFu + ((u >> 16) & 1u);   // round to nearest even
    return (ushortT)(u >> 16);
}
__device__ __forceinline__ float get1(const void* p, long i, int f) {
    return f ? ((const float*)p)[i] : bf2f(((const ushortT*)p)[i]);
}
__device__ __forceinline__ float4 get4(const void* p, long i, int f) {
    if (f) return *(const float4*)((const float*)p + i);
    ushort4 u = *(const ushort4*)((const ushortT*)p + i);
    return make_float4(bf2f(u.x), bf2f(u.y), bf2f(u.z), bf2f(u.w));
}
__device__ __forceinline__ float ld1c(const float* p)   { return *p; }
__device__ __forceinline__ float ld1c(const ushortT* p) { return bf2f(*p); }
__device__ __forceinline__ void st1c(float* p, float v)   { *p = v; }
__device__ __forceinline__ void st1c(ushortT* p, float v) { *p = f2bf(v); }
__device__ __forceinline__ int clampi(int v, int lo, int hi) {
    return v < lo ? lo : (v > hi ? hi : v);
}

// ---------------------------------------------------------------------------
// Float-input dtype detector (unchanged from R7 — validated).
// ---------------------------------------------------------------------------
__launch_bounds__(256)
__global__ void detect_k(const unsigned int* __restrict__ xw, int* __restrict__ flag)
{
    __shared__ int red[256];
    const int t = threadIdx.x;
    int hits = 0;
#pragma unroll
    for (int i = 0; i < 4; ++i) {
        const unsigned w = xw[t*4 + i];
        const unsigned eb = (w >> 7) & 0xFF;
        hits += (eb >= 100 && eb <= 150) ? 1 : 0;
    }
    red[t] = hits; __syncthreads();
#pragma unroll
    for (int s = 128; s > 0; s >>= 1) { if (t < s) red[t] += red[t+s]; __syncthreads(); }
    if (t == 0) *flag = (red[0] < 512) ? 1 : 0;
}

// ---------------------------------------------------------------------------
// MFMA GEMM: C = alpha*(A @ B[^T]) (+bias[biasOff+col]) (+C) (relu?)
// 64x64 tile/block, 4 waves, wave = 16 rows x 64 cols (4x 16x16x32 bf16 MFMA),
// K-step 32, fp32 accumulate. A/B staged to bf16 LDS (runtime src dtype).
// beOff = element offset into B (for qkvW column slices).
// Requires M%64==0, N%64==0, K%32==0.
// ---------------------------------------------------------------------------
template<class TC, bool BT, bool BIAS, bool RELU, bool RESID>
__launch_bounds__(256)
__global__ void gemm_k(const void* __restrict__ A, int cA,
                       const void* __restrict__ B, int cB, long beOff,
                       const void* __restrict__ bias, int cBias, long biasOff,
                       TC* __restrict__ C, const int* __restrict__ flagp,
                       int K, int lda, int ldb, int ldc,
                       long sA, long sB, long sC, float alpha)
{
    const int rtf = *flagp;
    const int fA = (cA == C_RT) ? rtf : cA;
    const int fB = (cB == C_RT) ? rtf : cB;

    const int t = threadIdx.x;
    const int lane = t & 63, wave = t >> 6;
    const int l15 = lane & 15, quad = lane >> 4;
    const int m0 = blockIdx.y * 64, n0 = blockIdx.x * 64;
    const long z = blockIdx.z;
    const long aOff = z * sA, bOff = beOff + z * sB, cOff = z * sC;

    __shared__ __align__(16) ushortT As[64][40];   // [m][k], stride 80B (16B-aligned rows)
    __shared__ __align__(16) ushortT Bs[64][40];   // [n][k]

    f32x4 acc[4] = {};   // 4 col-tiles x 4 rows/lane

    // staging index precompute
    const int ar = t >> 2, ak = (t & 3) * 8;        // A: row 0..63, k 0..31 (8/thread)
    const int bk = t & 31, bn = (t >> 5) * 8;       // B no-T: k 0..31, n 0..63 (8/thread)

    for (int k0 = 0; k0 < K; k0 += 32) {
        // ---- stage A tile ----
        {
            const long base = aOff + (long)(m0 + ar) * lda + (k0 + ak);
            float4 v0 = get4(A, base, fA);
            float4 v1 = get4(A, base + 4, fA);
            ushortT* dst = &As[ar][ak];
            dst[0]=f2bf(v0.x); dst[1]=f2bf(v0.y); dst[2]=f2bf(v0.z); dst[3]=f2bf(v0.w);
            dst[4]=f2bf(v1.x); dst[5]=f2bf(v1.y); dst[6]=f2bf(v1.z); dst[7]=f2bf(v1.w);
        }
        // ---- stage B tile into Bs[n][k] ----
        if constexpr (BT) {
            const long base = bOff + (long)(n0 + ar) * ldb + (k0 + ak);
            float4 v0 = get4(B, base, fB);
            float4 v1 = get4(B, base + 4, fB);
            ushortT* dst = &Bs[ar][ak];
            dst[0]=f2bf(v0.x); dst[1]=f2bf(v0.y); dst[2]=f2bf(v0.z); dst[3]=f2bf(v0.w);
            dst[4]=f2bf(v1.x); dst[5]=f2bf(v1.y); dst[6]=f2bf(v1.z); dst[7]=f2bf(v1.w);
        } else {
            const long base = bOff + (long)(k0 + bk) * ldb + (n0 + bn);
            float4 v0 = get4(B, base, fB);
            float4 v1 = get4(B, base + 4, fB);
            Bs[bn+0][bk] = f2bf(v0.x);
            Bs[bn+1][bk] = f2bf(v0.y);
            Bs[bn+2][bk] = f2bf(v0.z);
            Bs[bn+3][bk] = f2bf(v0.w);
            Bs[bn+4][bk] = f2bf(v1.x);
            Bs[bn+5][bk] = f2bf(v1.y);
            Bs[bn+6][bk] = f2bf(v1.z);
            Bs[bn+7][bk] = f2bf(v1.w);
        }
        __syncthreads();
        // ---- MFMA: wave handles rows [wave*16, wave*16+16), all 64 cols ----
        const bf16x8 af = *(const bf16x8*)&As[wave*16 + l15][quad*8];
#pragma unroll
        for (int nt = 0; nt < 4; ++nt) {
            const bf16x8 bf = *(const bf16x8*)&Bs[nt*16 + l15][quad*8];
            acc[nt] = __builtin_amdgcn_mfma_f32_16x16x32_bf16(af, bf, acc[nt], 0, 0, 0);
        }
        __syncthreads();
    }

    // ---- epilogue: D[row=quad*4+r][col=lane&15] per 16x16 tile ----
    const int fBias = BIAS ? ((cBias == C_RT) ? rtf : cBias) : 0;
#pragma unroll
    for (int nt = 0; nt < 4; ++nt) {
        const int col = n0 + nt*16 + l15;
        const float bv = BIAS ? get1(bias, biasOff + col, fBias) : 0.f;
#pragma unroll
        for (int r = 0; r < 4; ++r) {
            const int row = m0 + wave*16 + quad*4 + r;
            TC* cp = C + cOff + (long)row * ldc + col;
            float val = alpha * acc[nt][r] + bv;
            if constexpr (RESID) val += ld1c(cp);
            if constexpr (RELU)  val = fmaxf(val, 0.f);
            st1c(cp, val);
        }
    }
}

// ---------------- block reduction (256 threads) ----------------
__device__ __forceinline__ float blockReduceSum(float v, float* red, int t)
{
    red[t] = v; __syncthreads();
#pragma unroll
    for (int s = 128; s > 0; s >>= 1) {
        if (t < s) red[t] += red[t + s];
        __syncthreads();
    }
    const float r = red[0];
    __syncthreads();
    return r;
}

// ---------------------------------------------------------------------------
// gconv1 fused (unchanged from R7 — validated)
// ---------------------------------------------------------------------------
__launch_bounds__(256)
__global__ void gconv1_k(int b0, const void* __restrict__ x, const int* __restrict__ edges,
                         const void* __restrict__ ea,
                         const void* __restrict__ wembW, const void* __restrict__ wembB,
                         const void* __restrict__ Wrel, const void* __restrict__ brel,
                         const void* __restrict__ Wroot, ushortT* __restrict__ h1,
                         const int* __restrict__ flagp)
{
    const int f = *flagp;
    const int bl = blockIdx.x, g = b0 + bl, t = threadIdx.x;
    __shared__ float s_x[64][5];
    __shared__ float s_agg[64][5];
    __shared__ int   s_cnt[64];
    __shared__ int   s_off[65];
    __shared__ int   s_src[512];
    __shared__ float s_w[512];

    if (t < 64) s_cnt[t] = 0;
    if (t < 320) s_x[t/5][t%5] = get1(x, (long)(g*64 + t/5)*5 + (t%5), f);
    __syncthreads();

    const float w0 = get1(wembW,0,f), w1 = get1(wembW,1,f), w2 = get1(wembW,2,f);
    const float wb = get1(wembB,0,f);
    int sl[2], dl[2], slot[2]; float wv[2];
#pragma unroll
    for (int e2 = 0; e2 < 2; ++e2) {
        const int e = g*512 + t + 256*e2;
        const int s = edges[e], d = edges[EDIR + e];
        sl[e2] = clampi(s - g*64, 0, 63); dl[e2] = clampi(d - g*64, 0, 63);
        const float a0 = get1(ea, 2L*e, f), a1 = get1(ea, 2L*e+1, f);
        wv[e2] = fmaxf(a0*w0 + ((a1 < 0.5f) ? w1 : w2) + wb, 0.f);
        slot[e2] = atomicAdd(&s_cnt[dl[e2]], 1);
    }
    __syncthreads();
    if (t == 0) {
        int r = 0;
        for (int i = 0; i < 64; ++i) { s_off[i] = r; r += s_cnt[i]; }
        s_off[64] = r;
    }
    __syncthreads();
#pragma unroll
    for (int e2 = 0; e2 < 2; ++e2) {
        const int p = s_off[dl[e2]] + slot[e2];
        s_src[p] = sl[e2]; s_w[p] = wv[e2];
    }
    __syncthreads();
    if (t < 320) {
        const int n = t/5, k = t%5;
        float acc = 0.f;
        for (int i = s_off[n]; i < s_off[n+1]; ++i) acc += s_w[i] * s_x[s_src[i]][k];
        s_agg[n][k] = acc;
    }
    __syncthreads();
    float wr[5], wo[5];
#pragma unroll
    for (int k = 0; k < 5; ++k) { wr[k] = get1(Wrel, k*256 + t, f); wo[k] = get1(Wroot, k*256 + t, f); }
    const float bb = get1(brel, t, f);
    for (int n = 0; n < 64; ++n) {
        float v = bb;
#pragma unroll
        for (int k = 0; k < 5; ++k) v += s_agg[n][k]*wr[k] + s_x[n][k]*wo[k];
        h1[(bl*64 + n)*256 + t] = f2bf(fmaxf(v, 0.f));
    }
}

// ---------------------------------------------------------------------------
// gconv2 aggregation (unchanged from R7 — validated)
// ---------------------------------------------------------------------------
__launch_bounds__(256)
__global__ void gconv2_agg_k(int b0, const ushortT* __restrict__ h1, const int* __restrict__ edges,
                             const void* __restrict__ ea,
                             const void* __restrict__ wembW, const void* __restrict__ wembB,
                             ushortT* __restrict__ agg2, const int* __restrict__ flagp)
{
    const int f = *flagp;
    const int bl = blockIdx.x, g = b0 + bl, t = threadIdx.x;
    __shared__ int   s_cnt[64];
    __shared__ int   s_off[65];
    __shared__ int   s_src[512];
    __shared__ float s_w[512];

    if (t < 64) s_cnt[t] = 0;
    __syncthreads();

    const float w0 = get1(wembW,0,f), w1 = get1(wembW,1,f), w2 = get1(wembW,2,f);
    const float wb = get1(wembB,0,f);
    int sl[2], dl[2], slot[2]; float wv[2];
#pragma unroll
    for (int e2 = 0; e2 < 2; ++e2) {
        const int e = g*512 + t + 256*e2;
        const int s = edges[e], d = edges[EDIR + e];
        sl[e2] = clampi(s - g*64, 0, 63); dl[e2] = clampi(d - g*64, 0, 63);
        const float a0 = get1(ea, 2L*e, f), a1 = get1(ea, 2L*e+1, f);
        wv[e2] = fmaxf(a0*w0 + ((a1 < 0.5f) ? w1 : w2) + wb, 0.f);
        slot[e2] = atomicAdd(&s_cnt[dl[e2]], 1);
    }
    __syncthreads();
    if (t == 0) {
        int r = 0;
        for (int i = 0; i < 64; ++i) { s_off[i] = r; r += s_cnt[i]; }
        s_off[64] = r;
    }
    __syncthreads();
#pragma unroll
    for (int e2 = 0; e2 < 2; ++e2) {
        const int p = s_off[dl[e2]] + slot[e2];
        s_src[p] = sl[e2]; s_w[p] = wv[e2];
    }
    __syncthreads();
    for (int n = 0; n < 64; ++n) {
        float acc = 0.f;
        const int i0 = s_off[n], i1 = s_off[n+1];
        for (int i = i0; i < i1; ++i)
            acc += s_w[i] * bf2f(h1[(bl*64 + s_src[i])*256 + t]);
        agg2[(bl*64 + n)*256 + t] = f2bf(acc);
    }
}

// ---------------------------------------------------------------------------
// GraphNorm (unchanged from R7 — validated)
// ---------------------------------------------------------------------------
__launch_bounds__(256)
__global__ void gnorm_k(ushortT* __restrict__ h, const void* __restrict__ gw,
                        const void* __restrict__ gb, const void* __restrict__ gms,
                        const int* __restrict__ flagp)
{
    const int f0 = *flagp;
    const int bl = blockIdx.x, t = threadIdx.x;
#pragma unroll
    for (int f2 = 0; f2 < 2; ++f2) {
        const int f = t + 256*f2;
        float acc = 0.f;
        for (int n = 0; n < 64; ++n) acc += bf2f(h[(bl*64+n)*512 + f]);
        const float m2 = get1(gms, f, f0) * (acc * (1.f/64.f));
        float v = 0.f;
        for (int n = 0; n < 64; ++n) { const float d = bf2f(h[(bl*64+n)*512 + f]) - m2; v += d*d; }
        const float rs = rsqrtf(v*(1.f/64.f) + EPSC);
        const float g = get1(gw, f, f0), bb = get1(gb, f, f0);
        for (int n = 0; n < 64; ++n) {
            const int idx = (bl*64+n)*512 + f;
            h[idx] = f2bf(g * (bf2f(h[idx]) - m2) * rs + bb);
        }
    }
}

// ---------------------------------------------------------------------------
// SplitSyndromes sort (unchanged from R7 — validated by Output 0 passing)
// ---------------------------------------------------------------------------
__launch_bounds__(256)
__global__ void sort_k(const int* __restrict__ edges, int* __restrict__ sorted_orig,
                       int* __restrict__ se, int* __restrict__ te)
{
    const int b = blockIdx.x, t = threadIdx.x;
    __shared__ int s_keep[512];
    __shared__ int s_key[512];
    __shared__ int s_ckey[256];
    __shared__ int s_corig[256];
#pragma unroll
    for (int e2 = 0; e2 < 2; ++e2) {
        const int el = t + 256*e2;
        const int e = b*512 + el;
        const int s = edges[e], d = edges[EDIR + e];
        s_keep[el] = (s > d) ? 1 : 0;
        s_key[el]  = ((s - b*64) << 6) | (d - b*64);
    }
    __syncthreads();
#pragma unroll
    for (int e2 = 0; e2 < 2; ++e2) {
        const int el = t + 256*e2;
        if (s_keep[el]) {
            int pos = 0;
            for (int j = 0; j < el; ++j) pos += s_keep[j];
            s_ckey[pos]  = s_key[el];
            s_corig[pos] = b*512 + el;
        }
    }
    __syncthreads();
    const int ki = s_ckey[t];
    int rank = 0;
    for (int j = 0; j < 256; ++j) {
        const int kj = s_ckey[j];
        rank += (kj < ki || (kj == ki && j < t)) ? 1 : 0;
    }
    const int orig = s_corig[t];
    const int p = b*256 + rank;
    sorted_orig[p] = orig;
    se[p] = edges[orig];
    te[p] = edges[EDIR + orig];
}

// ---------------------------------------------------------------------------
// Build F_c (unchanged from R7 — validated)
// ---------------------------------------------------------------------------
__launch_bounds__(256)
__global__ void fbuild_k(int b0, int maxn, const ushortT* __restrict__ h,
                         const int* __restrict__ sorted_orig,
                         const int* __restrict__ se, const int* __restrict__ te,
                         const void* __restrict__ ea,
                         const void* __restrict__ eW, const void* __restrict__ eB,
                         ushortT* __restrict__ F, const int* __restrict__ flagp)
{
    const int fl = *flagp;
    const int e = blockIdx.x, t = threadIdx.x;
    const int ge = b0*256 + e;
    const int s = clampi(se[ge] - b0*64, 0, maxn);
    const int d = clampi(te[ge] - b0*64, 0, maxn);
    const int orig = clampi(sorted_orig[ge], 0, EDIR-1);
    const float a0 = get1(ea, 2L*orig, fl), a1 = get1(ea, 2L*orig + 1, fl);
#pragma unroll
    for (int c = 0; c < 6; ++c) {
        const int col = c*256 + t;
        float v;
        if (c < 2) {
            v = bf2f(h[(long)s*512 + col]);
        } else if (c < 4) {
            const int ff = col - 512;
            v = fmaxf(a0*get1(eW, ff, fl)
                      + ((a1 < 0.5f) ? get1(eW, 512+ff, fl) : get1(eW, 1024+ff, fl))
                      + get1(eB, ff, fl), 0.f);
        } else {
            v = bf2f(h[(long)d*512 + (col - 1024)]);
        }
        F[(long)e*1536 + col] = f2bf(v);
    }
}

// ---------------- row softmax (unchanged) ----------------
__launch_bounds__(256)
__global__ void softmax_k(float* __restrict__ S)
{
    const long row = blockIdx.x;
    const int t = threadIdx.x;
    __shared__ float red[256];
    const float v = S[row*256 + t];
    red[t] = v; __syncthreads();
#pragma unroll
    for (int s = 128; s > 0; s >>= 1) { if (t < s) red[t] = fmaxf(red[t], red[t+s]); __syncthreads(); }
    const float mx = red[0]; __syncthreads();
    const float e = __expf(v - mx);
    red[t] = e; __syncthreads();
#pragma unroll
    for (int s = 128; s > 0; s >>= 1) { if (t < s) red[t] += red[t+s]; __syncthreads(); }
    const float sum = red[0];
    S[row*256 + t] = e / sum;
}

// ---------------- fused LayerNorm + head dot (unchanged) ----------------
__launch_bounds__(256)
__global__ void ln_head_k(int b0, const ushortT* __restrict__ F, const void* __restrict__ lng,
                          const void* __restrict__ lnb, const void* __restrict__ hW,
                          const void* __restrict__ hB, float* __restrict__ gout,
                          const int* __restrict__ flagp)
{
    const int fl = *flagp;
    const int e = blockIdx.x, t = threadIdx.x;
    __shared__ float red[256];
    float xv[6];
    float s = 0.f;
#pragma unroll
    for (int c = 0; c < 6; ++c) { xv[c] = bf2f(F[(long)e*1536 + c*256 + t]); s += xv[c]; }
    const float tot = blockReduceSum(s, red, t);
    const float mu = tot * (1.f/1536.f);
    float ss = 0.f;
#pragma unroll
    for (int c = 0; c < 6; ++c) { const float d = xv[c] - mu; ss += d*d; }
    const float tot2 = blockReduceSum(ss, red, t);
    const float rs = rsqrtf(tot2 * (1.f/1536.f) + EPSC);
    float p = 0.f;
#pragma unroll
    for (int c = 0; c < 6; ++c) {
        const int col = c*256 + t;
        p += (get1(lng, col, fl) * (xv[c] - mu) * rs + get1(lnb, col, fl)) * get1(hW, col, fl);
    }
    const float tot3 = blockReduceSum(p, red, t);
    if (t == 0) gout[b0*256 + e] = tot3 + get1(hB, 0, fl);
}

// ---------------- final output assembly (unchanged) ----------------
__launch_bounds__(128)
__global__ void final_k(const float* __restrict__ gout, const int* __restrict__ se,
                        const int* __restrict__ te, const int* __restrict__ sorted_orig,
                        const void* __restrict__ ea, float* __restrict__ out,
                        const int* __restrict__ flagp)
{
    const int fl = *flagp;
    const int b = blockIdx.x, j = threadIdx.x;
    const int e0 = b*256 + 2*j, e1 = e0 + 1;
    const float p0 = gout[e0], p1 = gout[e1];
    const int idx = (p1 < p0) ? 1 : 0;
    const float val = idx ? p1 : p0;
    const int eo = idx ? e1 : e0;
    const int orig = clampi(sorted_orig[eo], 0, EDIR-1);
    const float cls = get1(ea, 2L*orig + 1, fl);
    out[(b*128 + j)*2 + 0] = (float)se[e0];
    out[(b*128 + j)*2 + 1] = (float)te[e0];
    out[32768 + b*128 + j] = val;
    out[32768 + 16384 + b*128 + j] = cls;
}

// ---------------------------------------------------------------------------
// Launch (structure identical to passing R7; gemm calls swapped to MFMA;
// K/V qkv slices now correctly offset via beOff/biasOff).
// ---------------------------------------------------------------------------
extern "C" void kernel_launch(void* const* d_in, const int* in_sizes, int n_in,
                              void* d_out, int out_size, void* d_ws, size_t ws_size,
                              hipStream_t stream)
{
    (void)out_size;

    const void* x     = d_in[0];
    const int*  edges = (const int*)d_in[1];
    const void* ea    = d_in[2];

    int ws0 = 3;
    while (ws0 < n_in && in_sizes[ws0] != 3) ++ws0;
    if (ws0 + 27 > n_in) ws0 = 5;

    const void* wembW  = d_in[ws0 + 0];
    const void* wembB  = d_in[ws0 + 1];
    const void* g1Wrel = d_in[ws0 + 2];
    const void* g1brel = d_in[ws0 + 3];
    const void* g1Wroot= d_in[ws0 + 4];
    const void* g2Wrel = d_in[ws0 + 5];
    const void* g2brel = d_in[ws0 + 6];
    const void* g2Wroot= d_in[ws0 + 7];
    const void* gnw    = d_in[ws0 + 8];
    const void* gnb    = d_in[ws0 + 9];
    const void* gnms   = d_in[ws0 + 10];
    const void* eembW  = d_in[ws0 + 11];
    const void* eembB  = d_in[ws0 + 12];
    const void* qkvW   = d_in[ws0 + 13];
    const void* qkvb   = d_in[ws0 + 14];
    const void* inWq   = d_in[ws0 + 15];
    const void* inWk   = d_in[ws0 + 16];
    const void* inWv   = d_in[ws0 + 17];
    const void* inbq   = d_in[ws0 + 18];
    const void* inbk   = d_in[ws0 + 19];
    const void* inbv   = d_in[ws0 + 20];
    const void* outW   = d_in[ws0 + 21];
    const void* outb   = d_in[ws0 + 22];
    const void* lng    = d_in[ws0 + 23];
    const void* lnb    = d_in[ws0 + 24];
    const void* headW  = d_in[ws0 + 25];
    const void* headb  = d_in[ws0 + 26];

    char* ws = (char*)d_ws;
    size_t off = 0;
    auto alloc = [&](size_t bytes) {
        void* p = ws + off;
        off = (off + bytes + 255) & ~(size_t)255;
        return p;
    };
    int*   dflag  = (int*)  alloc(256);
    float* gout   = (float*)alloc(EKEEP*4);
    int*   sorted = (int*)  alloc(EKEEP*4);
    int*   seg    = (int*)  alloc(EKEEP*4);
    int*   teg    = (int*)  alloc(EKEEP*4);
    const size_t fixedB = off;

    const size_t perG = 64L*512*2 + 2L*64*256*2 + 5L*256*1536*2 + 256L*256*4;
    int G = 128;
    while (G > 1 && fixedB + (size_t)G*perG + 8192 > ws_size) G >>= 1;

    ushortT* h_c  = (ushortT*)alloc((size_t)G*64*512*2);
    ushortT* h1_c = (ushortT*)alloc((size_t)G*64*256*2);
    ushortT* ag_c = (ushortT*)alloc((size_t)G*64*256*2);
    ushortT* F_c  = (ushortT*)alloc((size_t)G*256*1536*2);
    ushortT* A_c  = (ushortT*)alloc((size_t)G*256*1536*2);
    ushortT* Q_c  = (ushortT*)alloc((size_t)G*256*1536*2);
    ushortT* K_c  = (ushortT*)alloc((size_t)G*256*1536*2);
    ushortT* V_c  = (ushortT*)alloc((size_t)G*256*1536*2);
    float*   S_c  = (float*)  alloc((size_t)G*256*256*4);

    const float scale = 0.02551551815399144f;  // 1/sqrt(1536)
    const dim3 blk(256);

    detect_k<<<1, blk, 0, stream>>>((const unsigned int*)x, dflag);
    sort_k<<<128, blk, 0, stream>>>(edges, sorted, seg, teg);

    const int nchunk = 128 / G;
    const int EC = G * 256;
    for (int c = 0; c < nchunk; ++c) {
        const int b0 = c * G;
        gconv1_k<<<G, blk, 0, stream>>>(b0, x, edges, ea, wembW, wembB,
                                        g1Wrel, g1brel, g1Wroot, h1_c, dflag);
        gconv2_agg_k<<<G, blk, 0, stream>>>(b0, h1_c, edges, ea, wembW, wembB, ag_c, dflag);
        // h = ag @ g2Wrel + g2brel ; h += relu after adding h1 @ g2Wroot
        gemm_k<ushortT,false,true,false,false><<<dim3(8,G,1), blk, 0, stream>>>(
            ag_c, C_BF, g2Wrel, C_RT, 0, g2brel, C_RT, 0, h_c, dflag,
            256, 256, 512, 512, 0,0,0, 1.f);
        gemm_k<ushortT,false,false,true,true><<<dim3(8,G,1), blk, 0, stream>>>(
            h1_c, C_BF, g2Wroot, C_RT, 0, (const void*)nullptr, C_BF, 0, h_c, dflag,
            256, 256, 512, 512, 0,0,0, 1.f);
        gnorm_k<<<G, blk, 0, stream>>>(h_c, gnw, gnb, gnms, dflag);
        fbuild_k<<<EC, blk, 0, stream>>>(b0, G*64-1, h_c, sorted, seg, teg, ea,
                                         eembW, eembB, F_c, dflag);
        // Q path: A = F@qkvW[:,0:1536]+qkvb[0:1536]; Q = A@inWq+inbq
        gemm_k<ushortT,false,true,false,false><<<dim3(24,G*4,1), blk, 0, stream>>>(
            F_c, C_BF, qkvW, C_RT, 0, qkvb, C_RT, 0, A_c, dflag,
            1536, 1536, 4608, 1536, 0,0,0, 1.f);
        gemm_k<ushortT,false,true,false,false><<<dim3(24,G*4,1), blk, 0, stream>>>(
            A_c, C_BF, inWq, C_RT, 0, inbq, C_RT, 0, Q_c, dflag,
            1536, 1536, 1536, 1536, 0,0,0, 1.f);
        // K path (proper column slice 1536:3072 via beOff; bias via biasOff-1536+col... biasOff indexes bias[biasOff+col], col 0..1535 here so biasOff=1536)
        gemm_k<ushortT,false,true,false,false><<<dim3(24,G*4,1), blk, 0, stream>>>(
            F_c, C_BF, qkvW, C_RT, 1536, qkvb, C_RT, 1536, A_c, dflag,
            1536, 1536, 4608, 1536, 0,0,0, 1.f);
        gemm_k<ushortT,false,true,false,false><<<dim3(24,G*4,1), blk, 0, stream>>>(
            A_c, C_BF, inWk, C_RT, 0, inbk, C_RT, 0, K_c, dflag,
            1536, 1536, 1536, 1536, 0,0,0, 1.f);
        // V path (slice 3072:4608)
        gemm_k<ushortT,false,true,false,false><<<dim3(24,G*4,1), blk, 0, stream>>>(
            F_c, C_BF, qkvW, C_RT, 3072, qkvb, C_RT, 3072, A_c, dflag,
            1536, 1536, 4608, 1536, 0,0,0, 1.f);
        gemm_k<ushortT,false,true,false,false><<<dim3(24,G*4,1), blk, 0, stream>>>(
            A_c, C_BF, inWv, C_RT, 0, inbv, C_RT, 0, V_c, dflag,
            1536, 1536, 1536, 1536, 0,0,0, 1.f);
        // S_b = scale * Q_b @ K_b^T
        gemm_k<float,true,false,false,false><<<dim3(4,4,G), blk, 0, stream>>>(
            Q_c, C_BF, K_c, C_BF, 0, (const void*)nullptr, C_BF, 0, S_c, dflag,
            1536, 1536, 1536, 256, 256L*1536, 256L*1536, 65536L, scale);
        softmax_k<<<EC, blk, 0, stream>>>(S_c);
        // R_b = P_b @ V_b -> A_c
        gemm_k<ushortT,false,false,false,false><<<dim3(24,4,G), blk, 0, stream>>>(
            S_c, C_F32, V_c, C_BF, 0, (const void*)nullptr, C_BF, 0, A_c, dflag,
            256, 256, 1536, 1536, 65536L, 256L*1536, 256L*1536, 1.f);
        // F += R @ out_W + out_b (residual)
        gemm_k<ushortT,false,true,false,true><<<dim3(24,G*4,1), blk, 0, stream>>>(
            A_c, C_BF, outW, C_RT, 0, outb, C_RT, 0, F_c, dflag,
            1536, 1536, 1536, 1536, 0,0,0, 1.f);
        ln_head_k<<<EC, blk, 0, stream>>>(b0, F_c, lng, lnb, headW, headb, gout, dflag);
    }

    final_k<<<128, dim3(128), 0, stream>>>(gout, seg, teg, sorted, ea, (float*)d_out, dflag);
}

// Round 9
// 3419.709 us; speedup vs baseline: 5.0463x; 1.9293x over previous
//
#include <hip/hip_runtime.h>
#include <math.h>

// Problem constants
#define NTOT   8192
#define BGR    128
#define NPER   64
#define EDIR   65536
#define EKEEP  32768
#define EPSC   1e-5f

typedef unsigned short ushortT;
typedef __attribute__((ext_vector_type(8))) short bf16x8;
typedef __attribute__((ext_vector_type(4))) float f32x4;

// Operand dtype codes: 0 = bf16, 1 = f32, 2 = runtime (read *flagp)
#define C_BF 0
#define C_F32 1
#define C_RT 2

// ---------------- dtype helpers ----------------
__device__ __forceinline__ float bf2f(ushortT u) {
    union { unsigned int i; float f; } v; v.i = ((unsigned int)u) << 16; return v.f;
}
__device__ __forceinline__ ushortT f2bf(float f) {
    unsigned int u = __float_as_uint(f);
    u += 0x7FFFu + ((u >> 16) & 1u);   // round to nearest even
    return (ushortT)(u >> 16);
}
__device__ __forceinline__ float get1(const void* p, long i, int f) {
    return f ? ((const float*)p)[i] : bf2f(((const ushortT*)p)[i]);
}
__device__ __forceinline__ float4 get4(const void* p, long i, int f) {
    if (f) return *(const float4*)((const float*)p + i);
    ushort4 u = *(const ushort4*)((const ushortT*)p + i);
    return make_float4(bf2f(u.x), bf2f(u.y), bf2f(u.z), bf2f(u.w));
}
__device__ __forceinline__ float ld1c(const float* p)   { return *p; }
__device__ __forceinline__ float ld1c(const ushortT* p) { return bf2f(*p); }
__device__ __forceinline__ void st1c(float* p, float v)   { *p = v; }
__device__ __forceinline__ void st1c(ushortT* p, float v) { *p = f2bf(v); }
__device__ __forceinline__ int clampi(int v, int lo, int hi) {
    return v < lo ? lo : (v > hi ? hi : v);
}

// ---------------------------------------------------------------------------
// Float-input dtype detector (validated R7/R8).
// ---------------------------------------------------------------------------
__launch_bounds__(256)
__global__ void detect_k(const unsigned int* __restrict__ xw, int* __restrict__ flag)
{
    __shared__ int red[256];
    const int t = threadIdx.x;
    int hits = 0;
#pragma unroll
    for (int i = 0; i < 4; ++i) {
        const unsigned w = xw[t*4 + i];
        const unsigned eb = (w >> 7) & 0xFF;
        hits += (eb >= 100 && eb <= 150) ? 1 : 0;
    }
    red[t] = hits; __syncthreads();
#pragma unroll
    for (int s = 128; s > 0; s >>= 1) { if (t < s) red[t] += red[t+s]; __syncthreads(); }
    if (t == 0) *flag = (red[0] < 512) ? 1 : 0;
}

// ---------------------------------------------------------------------------
// MFMA GEMM (validated R8 core; + aeOff for A slices, + per-z bias stride):
// C = alpha*(A @ B[^T]) (+bias[biasOff + z*bzStride + col]) (+C) (relu?)
// 64x64 tile/block, 4 waves, 16x16x32 bf16 MFMA, fp32 accumulate.
// ---------------------------------------------------------------------------
template<class TC, bool BT, bool BIAS, bool RELU, bool RESID>
__launch_bounds__(256)
__global__ void gemm_k(const void* __restrict__ A, int cA, long aeOff,
                       const void* __restrict__ B, int cB, long beOff,
                       const void* __restrict__ bias, int cBias, long biasOff, long bzStride,
                       TC* __restrict__ C, const int* __restrict__ flagp,
                       int K, int lda, int ldb, int ldc,
                       long sA, long sB, long sC, float alpha)
{
    const int rtf = *flagp;
    const int fA = (cA == C_RT) ? rtf : cA;
    const int fB = (cB == C_RT) ? rtf : cB;

    const int t = threadIdx.x;
    const int lane = t & 63, wave = t >> 6;
    const int l15 = lane & 15, quad = lane >> 4;
    const int m0 = blockIdx.y * 64, n0 = blockIdx.x * 64;
    const long z = blockIdx.z;
    const long aOff = aeOff + z * sA, bOff = beOff + z * sB, cOff = z * sC;

    __shared__ __align__(16) ushortT As[64][40];
    __shared__ __align__(16) ushortT Bs[64][40];

    f32x4 acc[4] = {};

    const int ar = t >> 2, ak = (t & 3) * 8;
    const int bk = t & 31, bn = (t >> 5) * 8;

    for (int k0 = 0; k0 < K; k0 += 32) {
        {
            const long base = aOff + (long)(m0 + ar) * lda + (k0 + ak);
            float4 v0 = get4(A, base, fA);
            float4 v1 = get4(A, base + 4, fA);
            ushortT* dst = &As[ar][ak];
            dst[0]=f2bf(v0.x); dst[1]=f2bf(v0.y); dst[2]=f2bf(v0.z); dst[3]=f2bf(v0.w);
            dst[4]=f2bf(v1.x); dst[5]=f2bf(v1.y); dst[6]=f2bf(v1.z); dst[7]=f2bf(v1.w);
        }
        if constexpr (BT) {
            const long base = bOff + (long)(n0 + ar) * ldb + (k0 + ak);
            float4 v0 = get4(B, base, fB);
            float4 v1 = get4(B, base + 4, fB);
            ushortT* dst = &Bs[ar][ak];
            dst[0]=f2bf(v0.x); dst[1]=f2bf(v0.y); dst[2]=f2bf(v0.z); dst[3]=f2bf(v0.w);
            dst[4]=f2bf(v1.x); dst[5]=f2bf(v1.y); dst[6]=f2bf(v1.z); dst[7]=f2bf(v1.w);
        } else {
            const long base = bOff + (long)(k0 + bk) * ldb + (n0 + bn);
            float4 v0 = get4(B, base, fB);
            float4 v1 = get4(B, base + 4, fB);
            Bs[bn+0][bk] = f2bf(v0.x);
            Bs[bn+1][bk] = f2bf(v0.y);
            Bs[bn+2][bk] = f2bf(v0.z);
            Bs[bn+3][bk] = f2bf(v0.w);
            Bs[bn+4][bk] = f2bf(v1.x);
            Bs[bn+5][bk] = f2bf(v1.y);
            Bs[bn+6][bk] = f2bf(v1.z);
            Bs[bn+7][bk] = f2bf(v1.w);
        }
        __syncthreads();
        const bf16x8 af = *(const bf16x8*)&As[wave*16 + l15][quad*8];
#pragma unroll
        for (int nt = 0; nt < 4; ++nt) {
            const bf16x8 bf = *(const bf16x8*)&Bs[nt*16 + l15][quad*8];
            acc[nt] = __builtin_amdgcn_mfma_f32_16x16x32_bf16(af, bf, acc[nt], 0, 0, 0);
        }
        __syncthreads();
    }

    const int fBias = BIAS ? ((cBias == C_RT) ? rtf : cBias) : 0;
#pragma unroll
    for (int nt = 0; nt < 4; ++nt) {
        const int col = n0 + nt*16 + l15;
        const float bv = BIAS ? get1(bias, biasOff + z*bzStride + col, fBias) : 0.f;
#pragma unroll
        for (int r = 0; r < 4; ++r) {
            const int row = m0 + wave*16 + quad*4 + r;
            TC* cp = C + cOff + (long)row * ldc + col;
            float val = alpha * acc[nt][r] + bv;
            if constexpr (RESID) val += ld1c(cp);
            if constexpr (RELU)  val = fmaxf(val, 0.f);
            st1c(cp, val);
        }
    }
}

// ---------------- block reduction (256 threads) ----------------
__device__ __forceinline__ float blockReduceSum(float v, float* red, int t)
{
    red[t] = v; __syncthreads();
#pragma unroll
    for (int s = 128; s > 0; s >>= 1) {
        if (t < s) red[t] += red[t + s];
        __syncthreads();
    }
    const float r = red[0];
    __syncthreads();
    return r;
}

// ---------------------------------------------------------------------------
// colcomb: out[d] = sum_c v[voff+c] * W[c*1536+d] + b[d]   (f32 out), grid 6x256
// ---------------------------------------------------------------------------
__launch_bounds__(256)
__global__ void colcomb_k(const void* __restrict__ v, int cv, long voff,
                          const void* __restrict__ W, int cW,
                          const void* __restrict__ b, int cb,
                          float* __restrict__ out, const int* __restrict__ flagp)
{
    const int rtf = *flagp;
    const int fv = (cv == C_RT) ? rtf : cv;
    const int fW = (cW == C_RT) ? rtf : cW;
    const int fb = (cb == C_RT) ? rtf : cb;
    const int d = blockIdx.x*256 + threadIdx.x;
    float a0 = 0.f, a1 = 0.f;
    for (int c = 0; c < 1536; c += 2) {
        a0 += get1(v, voff+c+0, fv) * get1(W, (long)(c+0)*1536 + d, fW);
        a1 += get1(v, voff+c+1, fv) * get1(W, (long)(c+1)*1536 + d, fW);
    }
    out[d] = a0 + a1 + get1(b, d, fb);
}

// ---------------------------------------------------------------------------
// rowdot: out[r] = scale * sum_c bf2f(W[r*1536+c]) * v[c]   grid 1536 x 256
// ---------------------------------------------------------------------------
__launch_bounds__(256)
__global__ void rowdot_k(const ushortT* __restrict__ W, const float* __restrict__ v,
                         float* __restrict__ out, float scale)
{
    const int r = blockIdx.x, t = threadIdx.x;
    __shared__ float red[256];
    float p = 0.f;
    for (int c = t; c < 1536; c += 256) p += bf2f(W[(long)r*1536 + c]) * v[c];
    const float tot = blockReduceSum(p, red, t);
    if (t == 0) out[r] = scale * tot;
}

// ---------------------------------------------------------------------------
// gconv1 fused (unchanged — validated)
// ---------------------------------------------------------------------------
__launch_bounds__(256)
__global__ void gconv1_k(int b0, const void* __restrict__ x, const int* __restrict__ edges,
                         const void* __restrict__ ea,
                         const void* __restrict__ wembW, const void* __restrict__ wembB,
                         const void* __restrict__ Wrel, const void* __restrict__ brel,
                         const void* __restrict__ Wroot, ushortT* __restrict__ h1,
                         const int* __restrict__ flagp)
{
    const int f = *flagp;
    const int bl = blockIdx.x, g = b0 + bl, t = threadIdx.x;
    __shared__ float s_x[64][5];
    __shared__ float s_agg[64][5];
    __shared__ int   s_cnt[64];
    __shared__ int   s_off[65];
    __shared__ int   s_src[512];
    __shared__ float s_w[512];

    if (t < 64) s_cnt[t] = 0;
    if (t < 320) s_x[t/5][t%5] = get1(x, (long)(g*64 + t/5)*5 + (t%5), f);
    __syncthreads();

    const float w0 = get1(wembW,0,f), w1 = get1(wembW,1,f), w2 = get1(wembW,2,f);
    const float wb = get1(wembB,0,f);
    int sl[2], dl[2], slot[2]; float wv[2];
#pragma unroll
    for (int e2 = 0; e2 < 2; ++e2) {
        const int e = g*512 + t + 256*e2;
        const int s = edges[e], d = edges[EDIR + e];
        sl[e2] = clampi(s - g*64, 0, 63); dl[e2] = clampi(d - g*64, 0, 63);
        const float a0 = get1(ea, 2L*e, f), a1 = get1(ea, 2L*e+1, f);
        wv[e2] = fmaxf(a0*w0 + ((a1 < 0.5f) ? w1 : w2) + wb, 0.f);
        slot[e2] = atomicAdd(&s_cnt[dl[e2]], 1);
    }
    __syncthreads();
    if (t == 0) {
        int r = 0;
        for (int i = 0; i < 64; ++i) { s_off[i] = r; r += s_cnt[i]; }
        s_off[64] = r;
    }
    __syncthreads();
#pragma unroll
    for (int e2 = 0; e2 < 2; ++e2) {
        const int p = s_off[dl[e2]] + slot[e2];
        s_src[p] = sl[e2]; s_w[p] = wv[e2];
    }
    __syncthreads();
    if (t < 320) {
        const int n = t/5, k = t%5;
        float acc = 0.f;
        for (int i = s_off[n]; i < s_off[n+1]; ++i) acc += s_w[i] * s_x[s_src[i]][k];
        s_agg[n][k] = acc;
    }
    __syncthreads();
    float wr[5], wo[5];
#pragma unroll
    for (int k = 0; k < 5; ++k) { wr[k] = get1(Wrel, k*256 + t, f); wo[k] = get1(Wroot, k*256 + t, f); }
    const float bb = get1(brel, t, f);
    for (int n = 0; n < 64; ++n) {
        float v = bb;
#pragma unroll
        for (int k = 0; k < 5; ++k) v += s_agg[n][k]*wr[k] + s_x[n][k]*wo[k];
        h1[(bl*64 + n)*256 + t] = f2bf(fmaxf(v, 0.f));
    }
}

// ---------------------------------------------------------------------------
// gconv2 aggregation (unchanged — validated)
// ---------------------------------------------------------------------------
__launch_bounds__(256)
__global__ void gconv2_agg_k(int b0, const ushortT* __restrict__ h1, const int* __restrict__ edges,
                             const void* __restrict__ ea,
                             const void* __restrict__ wembW, const void* __restrict__ wembB,
                             ushortT* __restrict__ agg2, const int* __restrict__ flagp)
{
    const int f = *flagp;
    const int bl = blockIdx.x, g = b0 + bl, t = threadIdx.x;
    __shared__ int   s_cnt[64];
    __shared__ int   s_off[65];
    __shared__ int   s_src[512];
    __shared__ float s_w[512];

    if (t < 64) s_cnt[t] = 0;
    __syncthreads();

    const float w0 = get1(wembW,0,f), w1 = get1(wembW,1,f), w2 = get1(wembW,2,f);
    const float wb = get1(wembB,0,f);
    int sl[2], dl[2], slot[2]; float wv[2];
#pragma unroll
    for (int e2 = 0; e2 < 2; ++e2) {
        const int e = g*512 + t + 256*e2;
        const int s = edges[e], d = edges[EDIR + e];
        sl[e2] = clampi(s - g*64, 0, 63); dl[e2] = clampi(d - g*64, 0, 63);
        const float a0 = get1(ea, 2L*e, f), a1 = get1(ea, 2L*e+1, f);
        wv[e2] = fmaxf(a0*w0 + ((a1 < 0.5f) ? w1 : w2) + wb, 0.f);
        slot[e2] = atomicAdd(&s_cnt[dl[e2]], 1);
    }
    __syncthreads();
    if (t == 0) {
        int r = 0;
        for (int i = 0; i < 64; ++i) { s_off[i] = r; r += s_cnt[i]; }
        s_off[64] = r;
    }
    __syncthreads();
#pragma unroll
    for (int e2 = 0; e2 < 2; ++e2) {
        const int p = s_off[dl[e2]] + slot[e2];
        s_src[p] = sl[e2]; s_w[p] = wv[e2];
    }
    __syncthreads();
    for (int n = 0; n < 64; ++n) {
        float acc = 0.f;
        const int i0 = s_off[n], i1 = s_off[n+1];
        for (int i = i0; i < i1; ++i)
            acc += s_w[i] * bf2f(h1[(bl*64 + s_src[i])*256 + t]);
        agg2[(bl*64 + n)*256 + t] = f2bf(acc);
    }
}

// ---------------------------------------------------------------------------
// GraphNorm (unchanged — validated)
// ---------------------------------------------------------------------------
__launch_bounds__(256)
__global__ void gnorm_k(ushortT* __restrict__ h, const void* __restrict__ gw,
                        const void* __restrict__ gb, const void* __restrict__ gms,
                        const int* __restrict__ flagp)
{
    const int f0 = *flagp;
    const int bl = blockIdx.x, t = threadIdx.x;
#pragma unroll
    for (int f2 = 0; f2 < 2; ++f2) {
        const int f = t + 256*f2;
        float acc = 0.f;
        for (int n = 0; n < 64; ++n) acc += bf2f(h[(bl*64+n)*512 + f]);
        const float m2 = get1(gms, f, f0) * (acc * (1.f/64.f));
        float v = 0.f;
        for (int n = 0; n < 64; ++n) { const float d = bf2f(h[(bl*64+n)*512 + f]) - m2; v += d*d; }
        const float rs = rsqrtf(v*(1.f/64.f) + EPSC);
        const float g = get1(gw, f, f0), bb = get1(gb, f, f0);
        for (int n = 0; n < 64; ++n) {
            const int idx = (bl*64+n)*512 + f;
            h[idx] = f2bf(g * (bf2f(h[idx]) - m2) * rs + bb);
        }
    }
}

// ---------------------------------------------------------------------------
// SplitSyndromes sort (unchanged — validated)
// ---------------------------------------------------------------------------
__launch_bounds__(256)
__global__ void sort_k(const int* __restrict__ edges, int* __restrict__ sorted_orig,
                       int* __restrict__ se, int* __restrict__ te)
{
    const int b = blockIdx.x, t = threadIdx.x;
    __shared__ int s_keep[512];
    __shared__ int s_key[512];
    __shared__ int s_ckey[256];
    __shared__ int s_corig[256];
#pragma unroll
    for (int e2 = 0; e2 < 2; ++e2) {
        const int el = t + 256*e2;
        const int e = b*512 + el;
        const int s = edges[e], d = edges[EDIR + e];
        s_keep[el] = (s > d) ? 1 : 0;
        s_key[el]  = ((s - b*64) << 6) | (d - b*64);
    }
    __syncthreads();
#pragma unroll
    for (int e2 = 0; e2 < 2; ++e2) {
        const int el = t + 256*e2;
        if (s_keep[el]) {
            int pos = 0;
            for (int j = 0; j < el; ++j) pos += s_keep[j];
            s_ckey[pos]  = s_key[el];
            s_corig[pos] = b*512 + el;
        }
    }
    __syncthreads();
    const int ki = s_ckey[t];
    int rank = 0;
    for (int j = 0; j < 256; ++j) {
        const int kj = s_ckey[j];
        rank += (kj < ki || (kj == ki && j < t)) ? 1 : 0;
    }
    const int orig = s_corig[t];
    const int p = b*256 + rank;
    sorted_orig[p] = orig;
    se[p] = edges[orig];
    te[p] = edges[EDIR + orig];
}

// ---------------------------------------------------------------------------
// Build F_c + bvec[ge] = F[e] . kb  (score column-bias, scale folded in kb)
// ---------------------------------------------------------------------------
__launch_bounds__(256)
__global__ void fbuild_k(int b0, int maxn, const ushortT* __restrict__ h,
                         const int* __restrict__ sorted_orig,
                         const int* __restrict__ se, const int* __restrict__ te,
                         const void* __restrict__ ea,
                         const void* __restrict__ eW, const void* __restrict__ eB,
                         const float* __restrict__ kb,
                         ushortT* __restrict__ F, float* __restrict__ bvec,
                         const int* __restrict__ flagp)
{
    const int fl = *flagp;
    const int e = blockIdx.x, t = threadIdx.x;
    __shared__ float red[256];
    const int ge = b0*256 + e;
    const int s = clampi(se[ge] - b0*64, 0, maxn);
    const int d = clampi(te[ge] - b0*64, 0, maxn);
    const int orig = clampi(sorted_orig[ge], 0, EDIR-1);
    const float a0 = get1(ea, 2L*orig, fl), a1 = get1(ea, 2L*orig + 1, fl);
    float partial = 0.f;
#pragma unroll
    for (int c = 0; c < 6; ++c) {
        const int col = c*256 + t;
        float v;
        if (c < 2) {
            v = bf2f(h[(long)s*512 + col]);
        } else if (c < 4) {
            const int ff = col - 512;
            v = fmaxf(a0*get1(eW, ff, fl)
                      + ((a1 < 0.5f) ? get1(eW, 512+ff, fl) : get1(eW, 1024+ff, fl))
                      + get1(eB, ff, fl), 0.f);
        } else {
            v = bf2f(h[(long)d*512 + (col - 1024)]);
        }
        F[(long)e*1536 + col] = f2bf(v);
        partial += v * kb[col];
    }
    const float tot = blockReduceSum(partial, red, t);
    if (t == 0) bvec[ge] = tot;
}

// ---------------- row softmax (unchanged — validated) ----------------
__launch_bounds__(256)
__global__ void softmax_k(float* __restrict__ S)
{
    const long row = blockIdx.x;
    const int t = threadIdx.x;
    __shared__ float red[256];
    const float v = S[row*256 + t];
    red[t] = v; __syncthreads();
#pragma unroll
    for (int s = 128; s > 0; s >>= 1) { if (t < s) red[t] = fmaxf(red[t], red[t+s]); __syncthreads(); }
    const float mx = red[0]; __syncthreads();
    const float e = __expf(v - mx);
    red[t] = e; __syncthreads();
#pragma unroll
    for (int s = 128; s > 0; s >>= 1) { if (t < s) red[t] += red[t+s]; __syncthreads(); }
    const float sum = red[0];
    S[row*256 + t] = e / sum;
}

// ---------------- fused LayerNorm + head dot (unchanged — validated) --------
__launch_bounds__(256)
__global__ void ln_head_k(int b0, const ushortT* __restrict__ F, const void* __restrict__ lng,
                          const void* __restrict__ lnb, const void* __restrict__ hW,
                          const void* __restrict__ hB, float* __restrict__ gout,
                          const int* __restrict__ flagp)
{
    const int fl = *flagp;
    const int e = blockIdx.x, t = threadIdx.x;
    __shared__ float red[256];
    float xv[6];
    float s = 0.f;
#pragma unroll
    for (int c = 0; c < 6; ++c) { xv[c] = bf2f(F[(long)e*1536 + c*256 + t]); s += xv[c]; }
    const float tot = blockReduceSum(s, red, t);
    const float mu = tot * (1.f/1536.f);
    float ss = 0.f;
#pragma unroll
    for (int c = 0; c < 6; ++c) { const float d = xv[c] - mu; ss += d*d; }
    const float tot2 = blockReduceSum(ss, red, t);
    const float rs = rsqrtf(tot2 * (1.f/1536.f) + EPSC);
    float p = 0.f;
#pragma unroll
    for (int c = 0; c < 6; ++c) {
        const int col = c*256 + t;
        p += (get1(lng, col, fl) * (xv[c] - mu) * rs + get1(lnb, col, fl)) * get1(hW, col, fl);
    }
    const float tot3 = blockReduceSum(p, red, t);
    if (t == 0) gout[b0*256 + e] = tot3 + get1(hB, 0, fl);
}

// ---------------- final output assembly (unchanged — validated) -------------
__launch_bounds__(128)
__global__ void final_k(const float* __restrict__ gout, const int* __restrict__ se,
                        const int* __restrict__ te, const int* __restrict__ sorted_orig,
                        const void* __restrict__ ea, float* __restrict__ out,
                        const int* __restrict__ flagp)
{
    const int fl = *flagp;
    const int b = blockIdx.x, j = threadIdx.x;
    const int e0 = b*256 + 2*j, e1 = e0 + 1;
    const float p0 = gout[e0], p1 = gout[e1];
    const int idx = (p1 < p0) ? 1 : 0;
    const float val = idx ? p1 : p0;
    const int eo = idx ? e1 : e0;
    const int orig = clampi(sorted_orig[eo], 0, EDIR-1);
    const float cls = get1(ea, 2L*orig + 1, fl);
    out[(b*128 + j)*2 + 0] = (float)se[e0];
    out[(b*128 + j)*2 + 1] = (float)te[e0];
    out[32768 + b*128 + j] = val;
    out[32768 + 16384 + b*128 + j] = cls;
}

// ---------------------------------------------------------------------------
// Launch: phase-W weight precombination (once) + per-chunk attention with
// q/k/v never materialized. Fixed ~10.6 MB; union = max(phaseW 14.2MB, G*1.97MB).
// ---------------------------------------------------------------------------
extern "C" void kernel_launch(void* const* d_in, const int* in_sizes, int n_in,
                              void* d_out, int out_size, void* d_ws, size_t ws_size,
                              hipStream_t stream)
{
    (void)out_size;

    const void* x     = d_in[0];
    const int*  edges = (const int*)d_in[1];
    const void* ea    = d_in[2];

    int ws0 = 3;
    while (ws0 < n_in && in_sizes[ws0] != 3) ++ws0;
    if (ws0 + 27 > n_in) ws0 = 5;

    const void* wembW  = d_in[ws0 + 0];
    const void* wembB  = d_in[ws0 + 1];
    const void* g1Wrel = d_in[ws0 + 2];
    const void* g1brel = d_in[ws0 + 3];
    const void* g1Wroot= d_in[ws0 + 4];
    const void* g2Wrel = d_in[ws0 + 5];
    const void* g2brel = d_in[ws0 + 6];
    const void* g2Wroot= d_in[ws0 + 7];
    const void* gnw    = d_in[ws0 + 8];
    const void* gnb    = d_in[ws0 + 9];
    const void* gnms   = d_in[ws0 + 10];
    const void* eembW  = d_in[ws0 + 11];
    const void* eembB  = d_in[ws0 + 12];
    const void* qkvW   = d_in[ws0 + 13];
    const void* qkvb   = d_in[ws0 + 14];
    const void* inWq   = d_in[ws0 + 15];
    const void* inWk   = d_in[ws0 + 16];
    const void* inWv   = d_in[ws0 + 17];
    const void* inbq   = d_in[ws0 + 18];
    // inbk (ws0+19): k-bias adds row-constant score terms -> drops in softmax
    const void* inbv   = d_in[ws0 + 20];
    const void* outW   = d_in[ws0 + 21];
    const void* outb   = d_in[ws0 + 22];
    const void* lng    = d_in[ws0 + 23];
    const void* lnb    = d_in[ws0 + 24];
    const void* headW  = d_in[ws0 + 25];
    const void* headb  = d_in[ws0 + 26];

    char* ws = (char*)d_ws;
    size_t off = 0;
    auto alloc = [&](size_t bytes) {
        void* p = ws + off;
        off = (off + bytes + 255) & ~(size_t)255;
        return p;
    };
    // ---- fixed region (~10.6 MB) ----
    int*     dflag  = (int*)    alloc(256);
    float*   gout   = (float*)  alloc(EKEEP*4);
    int*     sorted = (int*)    alloc(EKEEP*4);
    int*     seg    = (int*)    alloc(EKEEP*4);
    int*     teg    = (int*)    alloc(EKEEP*4);
    float*   bvec   = (float*)  alloc(EKEEP*4);
    float*   bqc    = (float*)  alloc(1536*4);
    float*   bvc    = (float*)  alloc(1536*4);
    float*   kb     = (float*)  alloc(1536*4);
    float*   bvo    = (float*)  alloc(1536*4);
    ushortT* Mp     = (ushortT*)alloc(1536L*1536*2);
    ushortT* Wvo    = (ushortT*)alloc(1536L*1536*2);
    const size_t fixedB = off;

    // union region: phase-W (Wqc|Wkc, Wvc reuses Wqc) vs chunk scratch
    char* uni = ws + off;
    ushortT* Wqc = (ushortT*)uni;
    ushortT* Wkc = (ushortT*)(uni + ((1536L*1536*2 + 255) & ~255L));
    ushortT* Wvc = Wqc;

    const size_t perG = 64L*512*2 + 2L*64*256*2 + 2L*256*1536*2 + 256L*256*4; // 1.97MB
    int G = 128;
    while (G > 1 && fixedB + (size_t)G*perG + 8192 > ws_size) G >>= 1;

    size_t coff = fixedB;
    auto calloc2 = [&](size_t bytes) {
        void* p = ws + coff;
        coff = (coff + bytes + 255) & ~(size_t)255;
        return p;
    };
    ushortT* h_c  = (ushortT*)calloc2((size_t)G*64*512*2);
    ushortT* h1_c = (ushortT*)calloc2((size_t)G*64*256*2);
    ushortT* ag_c = (ushortT*)calloc2((size_t)G*64*256*2);
    ushortT* F_c  = (ushortT*)calloc2((size_t)G*256*1536*2);
    ushortT* T_c  = (ushortT*)calloc2((size_t)G*256*1536*2);
    float*   S_c  = (float*)  calloc2((size_t)G*256*256*4);

    const float scale = 0.02551551815399144f;  // 1/sqrt(1536)
    const dim3 blk(256);

    detect_k<<<1, blk, 0, stream>>>((const unsigned int*)x, dflag);
    sort_k<<<128, blk, 0, stream>>>(edges, sorted, seg, teg);

    // ---- phase W: weight precombination ----
    // Wqc = qkvW[:,0:1536] @ inWq ; Wkc = qkvW[:,1536:3072] @ inWk
    gemm_k<ushortT,false,false,false,false><<<dim3(24,24,1), blk, 0, stream>>>(
        qkvW, C_RT, 0, inWq, C_RT, 0, (const void*)nullptr, C_BF, 0, 0,
        Wqc, dflag, 1536, 4608, 1536, 1536, 0,0,0, 1.f);
    gemm_k<ushortT,false,false,false,false><<<dim3(24,24,1), blk, 0, stream>>>(
        qkvW, C_RT, 1536, inWk, C_RT, 0, (const void*)nullptr, C_BF, 0, 0,
        Wkc, dflag, 1536, 4608, 1536, 1536, 0,0,0, 1.f);
    // bqc = qkvb[0:1536] @ inWq + inbq
    colcomb_k<<<6, blk, 0, stream>>>(qkvb, C_RT, 0, inWq, C_RT, inbq, C_RT, bqc, dflag);
    // Mp = scale * Wqc @ Wkc^T  (row-constant score terms drop in softmax)
    gemm_k<ushortT,true,false,false,false><<<dim3(24,24,1), blk, 0, stream>>>(
        Wqc, C_BF, 0, Wkc, C_BF, 0, (const void*)nullptr, C_BF, 0, 0,
        Mp, dflag, 1536, 1536, 1536, 1536, 0,0,0, scale);
    // kb = scale * Wkc @ bqc  (per-column score bias direction)
    rowdot_k<<<1536, blk, 0, stream>>>(Wkc, bqc, kb, scale);
    // Wvc = qkvW[:,3072:4608] @ inWv  (reuses Wqc slot)
    gemm_k<ushortT,false,false,false,false><<<dim3(24,24,1), blk, 0, stream>>>(
        qkvW, C_RT, 3072, inWv, C_RT, 0, (const void*)nullptr, C_BF, 0, 0,
        Wvc, dflag, 1536, 4608, 1536, 1536, 0,0,0, 1.f);
    // bvc = qkvb[3072:] @ inWv + inbv
    colcomb_k<<<6, blk, 0, stream>>>(qkvb, C_RT, 3072, inWv, C_RT, inbv, C_RT, bvc, dflag);
    // Wvo = Wvc @ outW ; bvo = bvc @ outW + outb  (softmax rows sum to 1)
    gemm_k<ushortT,false,false,false,false><<<dim3(24,24,1), blk, 0, stream>>>(
        Wvc, C_BF, 0, outW, C_RT, 0, (const void*)nullptr, C_BF, 0, 0,
        Wvo, dflag, 1536, 1536, 1536, 1536, 0,0,0, 1.f);
    colcomb_k<<<6, blk, 0, stream>>>(bvc, C_F32, 0, outW, C_RT, outb, C_RT, bvo, dflag);

    // ---- per-chunk pipeline ----
    const int nchunk = 128 / G;
    const int EC = G * 256;
    for (int c = 0; c < nchunk; ++c) {
        const int b0 = c * G;
        gconv1_k<<<G, blk, 0, stream>>>(b0, x, edges, ea, wembW, wembB,
                                        g1Wrel, g1brel, g1Wroot, h1_c, dflag);
        gconv2_agg_k<<<G, blk, 0, stream>>>(b0, h1_c, edges, ea, wembW, wembB, ag_c, dflag);
        gemm_k<ushortT,false,true,false,false><<<dim3(8,G,1), blk, 0, stream>>>(
            ag_c, C_BF, 0, g2Wrel, C_RT, 0, g2brel, C_RT, 0, 0, h_c, dflag,
            256, 256, 512, 512, 0,0,0, 1.f);
        gemm_k<ushortT,false,false,true,true><<<dim3(8,G,1), blk, 0, stream>>>(
            h1_c, C_BF, 0, g2Wroot, C_RT, 0, (const void*)nullptr, C_BF, 0, 0, h_c, dflag,
            256, 256, 512, 512, 0,0,0, 1.f);
        gnorm_k<<<G, blk, 0, stream>>>(h_c, gnw, gnb, gnms, dflag);
        fbuild_k<<<EC, blk, 0, stream>>>(b0, G*64-1, h_c, sorted, seg, teg, ea,
                                         eembW, eembB, kb, F_c, bvec, dflag);
        // T = F @ Mp
        gemm_k<ushortT,false,false,false,false><<<dim3(24,EC/64,1), blk, 0, stream>>>(
            F_c, C_BF, 0, Mp, C_BF, 0, (const void*)nullptr, C_BF, 0, 0, T_c, dflag,
            1536, 1536, 1536, 1536, 0,0,0, 1.f);
        // S_b = T_b @ F_b^T + bvec[b0*256 + z*256 + col]
        gemm_k<float,true,true,false,false><<<dim3(4,4,G), blk, 0, stream>>>(
            T_c, C_BF, 0, F_c, C_BF, 0, bvec + (long)b0*256, C_F32, 0, 256, S_c, dflag,
            1536, 1536, 1536, 256, 256L*1536, 256L*1536, 65536L, 1.f);
        softmax_k<<<EC, blk, 0, stream>>>(S_c);
        // R_b = P_b @ F_b  -> T_c (reuse)
        gemm_k<ushortT,false,false,false,false><<<dim3(24,4,G), blk, 0, stream>>>(
            S_c, C_F32, 0, F_c, C_BF, 0, (const void*)nullptr, C_BF, 0, 0, T_c, dflag,
            256, 256, 1536, 1536, 65536L, 256L*1536, 256L*1536, 1.f);
        // F += R @ Wvo + bvo   (residual + fused out-proj)
        gemm_k<ushortT,false,true,false,true><<<dim3(24,EC/64,1), blk, 0, stream>>>(
            T_c, C_BF, 0, Wvo, C_BF, 0, bvo, C_F32, 0, 0, F_c, dflag,
            1536, 1536, 1536, 1536, 0,0,0, 1.f);
        ln_head_k<<<EC, blk, 0, stream>>>(b0, F_c, lng, lnb, headW, headb, gout, dflag);
    }

    final_k<<<128, dim3(128), 0, stream>>>(gout, seg, teg, sorted, ea, (float*)d_out, dflag);
}

// Round 10
// 2411.760 us; speedup vs baseline: 7.1553x; 1.4179x over previous
//
#include <hip/hip_runtime.h>
#include <math.h>

// Problem constants
#define NTOT   8192
#define BGR    128
#define NPER   64
#define EDIR   65536
#define EKEEP  32768
#define EPSC   1e-5f

typedef unsigned short ushortT;
typedef __attribute__((ext_vector_type(8))) short bf16x8;
typedef __attribute__((ext_vector_type(4))) float f32x4;

// Operand dtype codes: 0 = bf16, 1 = f32, 2 = runtime (read *flagp)
#define C_BF 0
#define C_F32 1
#define C_RT 2

// ---------------- dtype helpers ----------------
__device__ __forceinline__ float bf2f(ushortT u) {
    union { unsigned int i; float f; } v; v.i = ((unsigned int)u) << 16; return v.f;
}
__device__ __forceinline__ ushortT f2bf(float f) {
    unsigned int u = __float_as_uint(f);
    u += 0x7FFFu + ((u >> 16) & 1u);   // round to nearest even
    return (ushortT)(u >> 16);
}
__device__ __forceinline__ float get1(const void* p, long i, int f) {
    return f ? ((const float*)p)[i] : bf2f(((const ushortT*)p)[i]);
}
__device__ __forceinline__ float4 get4(const void* p, long i, int f) {
    if (f) return *(const float4*)((const float*)p + i);
    ushort4 u = *(const ushort4*)((const ushortT*)p + i);
    return make_float4(bf2f(u.x), bf2f(u.y), bf2f(u.z), bf2f(u.w));
}
__device__ __forceinline__ float ld1c(const float* p)   { return *p; }
__device__ __forceinline__ float ld1c(const ushortT* p) { return bf2f(*p); }
__device__ __forceinline__ void st1c(float* p, float v)   { *p = v; }
__device__ __forceinline__ void st1c(ushortT* p, float v) { *p = f2bf(v); }
__device__ __forceinline__ int clampi(int v, int lo, int hi) {
    return v < lo ? lo : (v > hi ? hi : v);
}

// ---------------------------------------------------------------------------
// Float-input dtype detector (validated R7-R9).
// ---------------------------------------------------------------------------
__launch_bounds__(256)
__global__ void detect_k(const unsigned int* __restrict__ xw, int* __restrict__ flag)
{
    __shared__ int red[256];
    const int t = threadIdx.x;
    int hits = 0;
#pragma unroll
    for (int i = 0; i < 4; ++i) {
        const unsigned w = xw[t*4 + i];
        const unsigned eb = (w >> 7) & 0xFF;
        hits += (eb >= 100 && eb <= 150) ? 1 : 0;
    }
    red[t] = hits; __syncthreads();
#pragma unroll
    for (int s = 128; s > 0; s >>= 1) { if (t < s) red[t] += red[t+s]; __syncthreads(); }
    if (t == 0) *flag = (red[0] < 512) ? 1 : 0;
}

// ---------------------------------------------------------------------------
// Fast bf16 GEMM: C = alpha*(A @ B^T) (+bias f32) (+C). Both A and B read
// k-contiguous (B stored [n][k]). 128x128 tile/block, 4 waves (2x2), each
// wave 64x64 via 4x4 16x16x32 bf16 MFMA tiles, BK=32, fp32 accumulate.
// Requires M%128==0 (per batch), N%128==0, K%32==0, lda/ldb%8==0.
// ---------------------------------------------------------------------------
template<class TC, bool BIAS, bool RESID>
__launch_bounds__(256)
__global__ void bgemm_k(const ushortT* __restrict__ A, const ushortT* __restrict__ B,
                        const float* __restrict__ bias, TC* __restrict__ C,
                        int K, int lda, int ldb, int ldc,
                        long sA, long sB, long sC, long biasOff, long bzStride,
                        float alpha)
{
    const int t = threadIdx.x;
    const int lane = t & 63, wave = t >> 6;
    const int l15 = lane & 15, quad = lane >> 4;
    const int wr = (wave >> 1) * 64, wc = (wave & 1) * 64;
    const int m0 = blockIdx.y * 128, n0 = blockIdx.x * 128;
    const long z = blockIdx.z;
    const ushortT* Ab = A + z * sA;
    const ushortT* Bb = B + z * sB;

    __shared__ __align__(16) ushortT As[128][40];   // row stride 80B, +16B pad
    __shared__ __align__(16) ushortT Bs[128][40];

    f32x4 acc[4][4] = {};

    const int sr = t >> 2, sk = (t & 3) * 8;   // staging: 64 rows/pass, 16B per thread

    for (int k0 = 0; k0 < K; k0 += 32) {
        *(float4*)&As[sr][sk]      = *(const float4*)(Ab + (long)(m0 + sr) * lda + k0 + sk);
        *(float4*)&As[64 + sr][sk] = *(const float4*)(Ab + (long)(m0 + 64 + sr) * lda + k0 + sk);
        *(float4*)&Bs[sr][sk]      = *(const float4*)(Bb + (long)(n0 + sr) * ldb + k0 + sk);
        *(float4*)&Bs[64 + sr][sk] = *(const float4*)(Bb + (long)(n0 + 64 + sr) * ldb + k0 + sk);
        __syncthreads();
        bf16x8 af[4], bf[4];
#pragma unroll
        for (int i = 0; i < 4; ++i) {
            af[i] = *(const bf16x8*)&As[wr + i*16 + l15][quad*8];
            bf[i] = *(const bf16x8*)&Bs[wc + i*16 + l15][quad*8];
        }
#pragma unroll
        for (int mt = 0; mt < 4; ++mt)
#pragma unroll
            for (int nt = 0; nt < 4; ++nt)
                acc[mt][nt] = __builtin_amdgcn_mfma_f32_16x16x32_bf16(af[mt], bf[nt], acc[mt][nt], 0, 0, 0);
        __syncthreads();
    }

    TC* Cb = C + z * sC;
#pragma unroll
    for (int nt = 0; nt < 4; ++nt) {
        const int col = n0 + wc + nt*16 + l15;
        const float bv = BIAS ? bias[biasOff + z*bzStride + col] : 0.f;
#pragma unroll
        for (int mt = 0; mt < 4; ++mt) {
#pragma unroll
            for (int r = 0; r < 4; ++r) {
                const int row = m0 + wr + mt*16 + quad*4 + r;
                TC* cp = Cb + (long)row * ldc + col;
                float val = alpha * acc[mt][nt][r] + bv;
                if constexpr (RESID) val += ld1c(cp);
                st1c(cp, val);
            }
        }
    }
}

// ---------------------------------------------------------------------------
// Generic MFMA GEMM (validated R8/R9; + CT transposed-store flag):
// C = alpha*(A @ B[^T]) (+bias[biasOff + z*bzStride + col]) (+C) (relu?)
// 64x64 tile/block, 4 waves, 16x16x32 bf16 MFMA, fp32 accumulate.
// ---------------------------------------------------------------------------
template<class TC, bool BT, bool BIAS, bool RELU, bool RESID, bool CT>
__launch_bounds__(256)
__global__ void gemm_k(const void* __restrict__ A, int cA, long aeOff,
                       const void* __restrict__ B, int cB, long beOff,
                       const void* __restrict__ bias, int cBias, long biasOff, long bzStride,
                       TC* __restrict__ C, const int* __restrict__ flagp,
                       int K, int lda, int ldb, int ldc,
                       long sA, long sB, long sC, float alpha)
{
    const int rtf = *flagp;
    const int fA = (cA == C_RT) ? rtf : cA;
    const int fB = (cB == C_RT) ? rtf : cB;

    const int t = threadIdx.x;
    const int lane = t & 63, wave = t >> 6;
    const int l15 = lane & 15, quad = lane >> 4;
    const int m0 = blockIdx.y * 64, n0 = blockIdx.x * 64;
    const long z = blockIdx.z;
    const long aOff = aeOff + z * sA, bOff = beOff + z * sB, cOff = z * sC;

    __shared__ __align__(16) ushortT As[64][40];
    __shared__ __align__(16) ushortT Bs[64][40];

    f32x4 acc[4] = {};

    const int ar = t >> 2, ak = (t & 3) * 8;
    const int bk = t & 31, bn = (t >> 5) * 8;

    for (int k0 = 0; k0 < K; k0 += 32) {
        {
            const long base = aOff + (long)(m0 + ar) * lda + (k0 + ak);
            float4 v0 = get4(A, base, fA);
            float4 v1 = get4(A, base + 4, fA);
            ushortT* dst = &As[ar][ak];
            dst[0]=f2bf(v0.x); dst[1]=f2bf(v0.y); dst[2]=f2bf(v0.z); dst[3]=f2bf(v0.w);
            dst[4]=f2bf(v1.x); dst[5]=f2bf(v1.y); dst[6]=f2bf(v1.z); dst[7]=f2bf(v1.w);
        }
        if constexpr (BT) {
            const long base = bOff + (long)(n0 + ar) * ldb + (k0 + ak);
            float4 v0 = get4(B, base, fB);
            float4 v1 = get4(B, base + 4, fB);
            ushortT* dst = &Bs[ar][ak];
            dst[0]=f2bf(v0.x); dst[1]=f2bf(v0.y); dst[2]=f2bf(v0.z); dst[3]=f2bf(v0.w);
            dst[4]=f2bf(v1.x); dst[5]=f2bf(v1.y); dst[6]=f2bf(v1.z); dst[7]=f2bf(v1.w);
        } else {
            const long base = bOff + (long)(k0 + bk) * ldb + (n0 + bn);
            float4 v0 = get4(B, base, fB);
            float4 v1 = get4(B, base + 4, fB);
            Bs[bn+0][bk] = f2bf(v0.x);
            Bs[bn+1][bk] = f2bf(v0.y);
            Bs[bn+2][bk] = f2bf(v0.z);
            Bs[bn+3][bk] = f2bf(v0.w);
            Bs[bn+4][bk] = f2bf(v1.x);
            Bs[bn+5][bk] = f2bf(v1.y);
            Bs[bn+6][bk] = f2bf(v1.z);
            Bs[bn+7][bk] = f2bf(v1.w);
        }
        __syncthreads();
        const bf16x8 af = *(const bf16x8*)&As[wave*16 + l15][quad*8];
#pragma unroll
        for (int nt = 0; nt < 4; ++nt) {
            const bf16x8 bf = *(const bf16x8*)&Bs[nt*16 + l15][quad*8];
            acc[nt] = __builtin_amdgcn_mfma_f32_16x16x32_bf16(af, bf, acc[nt], 0, 0, 0);
        }
        __syncthreads();
    }

    const int fBias = BIAS ? ((cBias == C_RT) ? rtf : cBias) : 0;
#pragma unroll
    for (int nt = 0; nt < 4; ++nt) {
        const int col = n0 + nt*16 + l15;
        const float bv = BIAS ? get1(bias, biasOff + z*bzStride + col, fBias) : 0.f;
#pragma unroll
        for (int r = 0; r < 4; ++r) {
            const int row = m0 + wave*16 + quad*4 + r;
            TC* cp = CT ? (C + cOff + (long)col * ldc + row)
                        : (C + cOff + (long)row * ldc + col);
            float val = alpha * acc[nt][r] + bv;
            if constexpr (RESID) val += ld1c(cp);
            if constexpr (RELU)  val = fmaxf(val, 0.f);
            st1c(cp, val);
        }
    }
}

// ---------------- block reduction (256 threads) ----------------
__device__ __forceinline__ float blockReduceSum(float v, float* red, int t)
{
    red[t] = v; __syncthreads();
#pragma unroll
    for (int s = 128; s > 0; s >>= 1) {
        if (t < s) red[t] += red[t + s];
        __syncthreads();
    }
    const float r = red[0];
    __syncthreads();
    return r;
}

// ---------------------------------------------------------------------------
// colcomb: out[d] = sum_c v[voff+c] * W[c*1536+d] + b[d]   (f32 out), grid 6x256
// ---------------------------------------------------------------------------
__launch_bounds__(256)
__global__ void colcomb_k(const void* __restrict__ v, int cv, long voff,
                          const void* __restrict__ W, int cW,
                          const void* __restrict__ b, int cb,
                          float* __restrict__ out, const int* __restrict__ flagp)
{
    const int rtf = *flagp;
    const int fv = (cv == C_RT) ? rtf : cv;
    const int fW = (cW == C_RT) ? rtf : cW;
    const int fb = (cb == C_RT) ? rtf : cb;
    const int d = blockIdx.x*256 + threadIdx.x;
    float a0 = 0.f, a1 = 0.f;
    for (int c = 0; c < 1536; c += 2) {
        a0 += get1(v, voff+c+0, fv) * get1(W, (long)(c+0)*1536 + d, fW);
        a1 += get1(v, voff+c+1, fv) * get1(W, (long)(c+1)*1536 + d, fW);
    }
    out[d] = a0 + a1 + get1(b, d, fb);
}

// ---------------------------------------------------------------------------
// rowdot: out[r] = scale * sum_c bf2f(W[r*1536+c]) * v[c]   grid 1536 x 256
// ---------------------------------------------------------------------------
__launch_bounds__(256)
__global__ void rowdot_k(const ushortT* __restrict__ W, const float* __restrict__ v,
                         float* __restrict__ out, float scale)
{
    const int r = blockIdx.x, t = threadIdx.x;
    __shared__ float red[256];
    float p = 0.f;
    for (int c = t; c < 1536; c += 256) p += bf2f(W[(long)r*1536 + c]) * v[c];
    const float tot = blockReduceSum(p, red, t);
    if (t == 0) out[r] = scale * tot;
}

// ---------------------------------------------------------------------------
// gconv1 fused (unchanged — validated)
// ---------------------------------------------------------------------------
__launch_bounds__(256)
__global__ void gconv1_k(int b0, const void* __restrict__ x, const int* __restrict__ edges,
                         const void* __restrict__ ea,
                         const void* __restrict__ wembW, const void* __restrict__ wembB,
                         const void* __restrict__ Wrel, const void* __restrict__ brel,
                         const void* __restrict__ Wroot, ushortT* __restrict__ h1,
                         const int* __restrict__ flagp)
{
    const int f = *flagp;
    const int bl = blockIdx.x, g = b0 + bl, t = threadIdx.x;
    __shared__ float s_x[64][5];
    __shared__ float s_agg[64][5];
    __shared__ int   s_cnt[64];
    __shared__ int   s_off[65];
    __shared__ int   s_src[512];
    __shared__ float s_w[512];

    if (t < 64) s_cnt[t] = 0;
    if (t < 320) s_x[t/5][t%5] = get1(x, (long)(g*64 + t/5)*5 + (t%5), f);
    __syncthreads();

    const float w0 = get1(wembW,0,f), w1 = get1(wembW,1,f), w2 = get1(wembW,2,f);
    const float wb = get1(wembB,0,f);
    int sl[2], dl[2], slot[2]; float wv[2];
#pragma unroll
    for (int e2 = 0; e2 < 2; ++e2) {
        const int e = g*512 + t + 256*e2;
        const int s = edges[e], d = edges[EDIR + e];
        sl[e2] = clampi(s - g*64, 0, 63); dl[e2] = clampi(d - g*64, 0, 63);
        const float a0 = get1(ea, 2L*e, f), a1 = get1(ea, 2L*e+1, f);
        wv[e2] = fmaxf(a0*w0 + ((a1 < 0.5f) ? w1 : w2) + wb, 0.f);
        slot[e2] = atomicAdd(&s_cnt[dl[e2]], 1);
    }
    __syncthreads();
    if (t == 0) {
        int r = 0;
        for (int i = 0; i < 64; ++i) { s_off[i] = r; r += s_cnt[i]; }
        s_off[64] = r;
    }
    __syncthreads();
#pragma unroll
    for (int e2 = 0; e2 < 2; ++e2) {
        const int p = s_off[dl[e2]] + slot[e2];
        s_src[p] = sl[e2]; s_w[p] = wv[e2];
    }
    __syncthreads();
    if (t < 320) {
        const int n = t/5, k = t%5;
        float acc = 0.f;
        for (int i = s_off[n]; i < s_off[n+1]; ++i) acc += s_w[i] * s_x[s_src[i]][k];
        s_agg[n][k] = acc;
    }
    __syncthreads();
    float wr[5], wo[5];
#pragma unroll
    for (int k = 0; k < 5; ++k) { wr[k] = get1(Wrel, k*256 + t, f); wo[k] = get1(Wroot, k*256 + t, f); }
    const float bb = get1(brel, t, f);
    for (int n = 0; n < 64; ++n) {
        float v = bb;
#pragma unroll
        for (int k = 0; k < 5; ++k) v += s_agg[n][k]*wr[k] + s_x[n][k]*wo[k];
        h1[(bl*64 + n)*256 + t] = f2bf(fmaxf(v, 0.f));
    }
}

// ---------------------------------------------------------------------------
// gconv2 aggregation (unchanged — validated)
// ---------------------------------------------------------------------------
__launch_bounds__(256)
__global__ void gconv2_agg_k(int b0, const ushortT* __restrict__ h1, const int* __restrict__ edges,
                             const void* __restrict__ ea,
                             const void* __restrict__ wembW, const void* __restrict__ wembB,
                             ushortT* __restrict__ agg2, const int* __restrict__ flagp)
{
    const int f = *flagp;
    const int bl = blockIdx.x, g = b0 + bl, t = threadIdx.x;
    __shared__ int   s_cnt[64];
    __shared__ int   s_off[65];
    __shared__ int   s_src[512];
    __shared__ float s_w[512];

    if (t < 64) s_cnt[t] = 0;
    __syncthreads();

    const float w0 = get1(wembW,0,f), w1 = get1(wembW,1,f), w2 = get1(wembW,2,f);
    const float wb = get1(wembB,0,f);
    int sl[2], dl[2], slot[2]; float wv[2];
#pragma unroll
    for (int e2 = 0; e2 < 2; ++e2) {
        const int e = g*512 + t + 256*e2;
        const int s = edges[e], d = edges[EDIR + e];
        sl[e2] = clampi(s - g*64, 0, 63); dl[e2] = clampi(d - g*64, 0, 63);
        const float a0 = get1(ea, 2L*e, f), a1 = get1(ea, 2L*e+1, f);
        wv[e2] = fmaxf(a0*w0 + ((a1 < 0.5f) ? w1 : w2) + wb, 0.f);
        slot[e2] = atomicAdd(&s_cnt[dl[e2]], 1);
    }
    __syncthreads();
    if (t == 0) {
        int r = 0;
        for (int i = 0; i < 64; ++i) { s_off[i] = r; r += s_cnt[i]; }
        s_off[64] = r;
    }
    __syncthreads();
#pragma unroll
    for (int e2 = 0; e2 < 2; ++e2) {
        const int p = s_off[dl[e2]] + slot[e2];
        s_src[p] = sl[e2]; s_w[p] = wv[e2];
    }
    __syncthreads();
    for (int n = 0; n < 64; ++n) {
        float acc = 0.f;
        const int i0 = s_off[n], i1 = s_off[n+1];
        for (int i = i0; i < i1; ++i)
            acc += s_w[i] * bf2f(h1[(bl*64 + s_src[i])*256 + t]);
        agg2[(bl*64 + n)*256 + t] = f2bf(acc);
    }
}

// ---------------------------------------------------------------------------
// GraphNorm (unchanged — validated)
// ---------------------------------------------------------------------------
__launch_bounds__(256)
__global__ void gnorm_k(ushortT* __restrict__ h, const void* __restrict__ gw,
                        const void* __restrict__ gb, const void* __restrict__ gms,
                        const int* __restrict__ flagp)
{
    const int f0 = *flagp;
    const int bl = blockIdx.x, t = threadIdx.x;
#pragma unroll
    for (int f2 = 0; f2 < 2; ++f2) {
        const int f = t + 256*f2;
        float acc = 0.f;
        for (int n = 0; n < 64; ++n) acc += bf2f(h[(bl*64+n)*512 + f]);
        const float m2 = get1(gms, f, f0) * (acc * (1.f/64.f));
        float v = 0.f;
        for (int n = 0; n < 64; ++n) { const float d = bf2f(h[(bl*64+n)*512 + f]) - m2; v += d*d; }
        const float rs = rsqrtf(v*(1.f/64.f) + EPSC);
        const float g = get1(gw, f, f0), bb = get1(gb, f, f0);
        for (int n = 0; n < 64; ++n) {
            const int idx = (bl*64+n)*512 + f;
            h[idx] = f2bf(g * (bf2f(h[idx]) - m2) * rs + bb);
        }
    }
}

// ---------------------------------------------------------------------------
// SplitSyndromes sort (unchanged — validated)
// ---------------------------------------------------------------------------
__launch_bounds__(256)
__global__ void sort_k(const int* __restrict__ edges, int* __restrict__ sorted_orig,
                       int* __restrict__ se, int* __restrict__ te)
{
    const int b = blockIdx.x, t = threadIdx.x;
    __shared__ int s_keep[512];
    __shared__ int s_key[512];
    __shared__ int s_ckey[256];
    __shared__ int s_corig[256];
#pragma unroll
    for (int e2 = 0; e2 < 2; ++e2) {
        const int el = t + 256*e2;
        const int e = b*512 + el;
        const int s = edges[e], d = edges[EDIR + e];
        s_keep[el] = (s > d) ? 1 : 0;
        s_key[el]  = ((s - b*64) << 6) | (d - b*64);
    }
    __syncthreads();
#pragma unroll
    for (int e2 = 0; e2 < 2; ++e2) {
        const int el = t + 256*e2;
        if (s_keep[el]) {
            int pos = 0;
            for (int j = 0; j < el; ++j) pos += s_keep[j];
            s_ckey[pos]  = s_key[el];
            s_corig[pos] = b*512 + el;
        }
    }
    __syncthreads();
    const int ki = s_ckey[t];
    int rank = 0;
    for (int j = 0; j < 256; ++j) {
        const int kj = s_ckey[j];
        rank += (kj < ki || (kj == ki && j < t)) ? 1 : 0;
    }
    const int orig = s_corig[t];
    const int p = b*256 + rank;
    sorted_orig[p] = orig;
    se[p] = edges[orig];
    te[p] = edges[EDIR + orig];
}

// ---------------------------------------------------------------------------
// Build F_c + bvec[ge] = F[e] . kb  (unchanged — validated)
// ---------------------------------------------------------------------------
__launch_bounds__(256)
__global__ void fbuild_k(int b0, int maxn, const ushortT* __restrict__ h,
                         const int* __restrict__ sorted_orig,
                         const int* __restrict__ se, const int* __restrict__ te,
                         const void* __restrict__ ea,
                         const void* __restrict__ eW, const void* __restrict__ eB,
                         const float* __restrict__ kb,
                         ushortT* __restrict__ F, float* __restrict__ bvec,
                         const int* __restrict__ flagp)
{
    const int fl = *flagp;
    const int e = blockIdx.x, t = threadIdx.x;
    __shared__ float red[256];
    const int ge = b0*256 + e;
    const int s = clampi(se[ge] - b0*64, 0, maxn);
    const int d = clampi(te[ge] - b0*64, 0, maxn);
    const int orig = clampi(sorted_orig[ge], 0, EDIR-1);
    const float a0 = get1(ea, 2L*orig, fl), a1 = get1(ea, 2L*orig + 1, fl);
    float partial = 0.f;
#pragma unroll
    for (int c = 0; c < 6; ++c) {
        const int col = c*256 + t;
        float v;
        if (c < 2) {
            v = bf2f(h[(long)s*512 + col]);
        } else if (c < 4) {
            const int ff = col - 512;
            v = fmaxf(a0*get1(eW, ff, fl)
                      + ((a1 < 0.5f) ? get1(eW, 512+ff, fl) : get1(eW, 1024+ff, fl))
                      + get1(eB, ff, fl), 0.f);
        } else {
            v = bf2f(h[(long)d*512 + (col - 1024)]);
        }
        F[(long)e*1536 + col] = f2bf(v);
        partial += v * kb[col];
    }
    const float tot = blockReduceSum(partial, red, t);
    if (t == 0) bvec[ge] = tot;
}

// ---------------- row softmax (unchanged — validated) ----------------
__launch_bounds__(256)
__global__ void softmax_k(float* __restrict__ S)
{
    const long row = blockIdx.x;
    const int t = threadIdx.x;
    __shared__ float red[256];
    const float v = S[row*256 + t];
    red[t] = v; __syncthreads();
#pragma unroll
    for (int s = 128; s > 0; s >>= 1) { if (t < s) red[t] = fmaxf(red[t], red[t+s]); __syncthreads(); }
    const float mx = red[0]; __syncthreads();
    const float e = __expf(v - mx);
    red[t] = e; __syncthreads();
#pragma unroll
    for (int s = 128; s > 0; s >>= 1) { if (t < s) red[t] += red[t+s]; __syncthreads(); }
    const float sum = red[0];
    S[row*256 + t] = e / sum;
}

// ---------------- fused LayerNorm + head dot (unchanged — validated) --------
__launch_bounds__(256)
__global__ void ln_head_k(int b0, const ushortT* __restrict__ F, const void* __restrict__ lng,
                          const void* __restrict__ lnb, const void* __restrict__ hW,
                          const void* __restrict__ hB, float* __restrict__ gout,
                          const int* __restrict__ flagp)
{
    const int fl = *flagp;
    const int e = blockIdx.x, t = threadIdx.x;
    __shared__ float red[256];
    float xv[6];
    float s = 0.f;
#pragma unroll
    for (int c = 0; c < 6; ++c) { xv[c] = bf2f(F[(long)e*1536 + c*256 + t]); s += xv[c]; }
    const float tot = blockReduceSum(s, red, t);
    const float mu = tot * (1.f/1536.f);
    float ss = 0.f;
#pragma unroll
    for (int c = 0; c < 6; ++c) { const float d = xv[c] - mu; ss += d*d; }
    const float tot2 = blockReduceSum(ss, red, t);
    const float rs = rsqrtf(tot2 * (1.f/1536.f) + EPSC);
    float p = 0.f;
#pragma unroll
    for (int c = 0; c < 6; ++c) {
        const int col = c*256 + t;
        p += (get1(lng, col, fl) * (xv[c] - mu) * rs + get1(lnb, col, fl)) * get1(hW, col, fl);
    }
    const float tot3 = blockReduceSum(p, red, t);
    if (t == 0) gout[b0*256 + e] = tot3 + get1(hB, 0, fl);
}

// ---------------- final output assembly (unchanged — validated) -------------
__launch_bounds__(128)
__global__ void final_k(const float* __restrict__ gout, const int* __restrict__ se,
                        const int* __restrict__ te, const int* __restrict__ sorted_orig,
                        const void* __restrict__ ea, float* __restrict__ out,
                        const int* __restrict__ flagp)
{
    const int fl = *flagp;
    const int b = blockIdx.x, j = threadIdx.x;
    const int e0 = b*256 + 2*j, e1 = e0 + 1;
    const float p0 = gout[e0], p1 = gout[e1];
    const int idx = (p1 < p0) ? 1 : 0;
    const float val = idx ? p1 : p0;
    const int eo = idx ? e1 : e0;
    const int orig = clampi(sorted_orig[eo], 0, EDIR-1);
    const float cls = get1(ea, 2L*orig + 1, fl);
    out[(b*128 + j)*2 + 0] = (float)se[e0];
    out[(b*128 + j)*2 + 1] = (float)te[e0];
    out[32768 + b*128 + j] = val;
    out[32768 + 16384 + b*128 + j] = cls;
}

// ---------------------------------------------------------------------------
// Launch: phase-W precombination emits MpT/WvoT (transposed, bf16) so the hot
// GEMMs run on the fast k-contiguous bf16 path.
// ---------------------------------------------------------------------------
extern "C" void kernel_launch(void* const* d_in, const int* in_sizes, int n_in,
                              void* d_out, int out_size, void* d_ws, size_t ws_size,
                              hipStream_t stream)
{
    (void)out_size;

    const void* x     = d_in[0];
    const int*  edges = (const int*)d_in[1];
    const void* ea    = d_in[2];

    int ws0 = 3;
    while (ws0 < n_in && in_sizes[ws0] != 3) ++ws0;
    if (ws0 + 27 > n_in) ws0 = 5;

    const void* wembW  = d_in[ws0 + 0];
    const void* wembB  = d_in[ws0 + 1];
    const void* g1Wrel = d_in[ws0 + 2];
    const void* g1brel = d_in[ws0 + 3];
    const void* g1Wroot= d_in[ws0 + 4];
    const void* g2Wrel = d_in[ws0 + 5];
    const void* g2brel = d_in[ws0 + 6];
    const void* g2Wroot= d_in[ws0 + 7];
    const void* gnw    = d_in[ws0 + 8];
    const void* gnb    = d_in[ws0 + 9];
    const void* gnms   = d_in[ws0 + 10];
    const void* eembW  = d_in[ws0 + 11];
    const void* eembB  = d_in[ws0 + 12];
    const void* qkvW   = d_in[ws0 + 13];
    const void* qkvb   = d_in[ws0 + 14];
    const void* inWq   = d_in[ws0 + 15];
    const void* inWk   = d_in[ws0 + 16];
    const void* inWv   = d_in[ws0 + 17];
    const void* inbq   = d_in[ws0 + 18];
    // inbk (ws0+19): row-constant score terms -> drop in softmax
    const void* inbv   = d_in[ws0 + 20];
    const void* outW   = d_in[ws0 + 21];
    const void* outb   = d_in[ws0 + 22];
    const void* lng    = d_in[ws0 + 23];
    const void* lnb    = d_in[ws0 + 24];
    const void* headW  = d_in[ws0 + 25];
    const void* headb  = d_in[ws0 + 26];

    char* ws = (char*)d_ws;
    size_t off = 0;
    auto alloc = [&](size_t bytes) {
        void* p = ws + off;
        off = (off + bytes + 255) & ~(size_t)255;
        return p;
    };
    // ---- fixed region (~10.6 MB) ----
    int*     dflag  = (int*)    alloc(256);
    float*   gout   = (float*)  alloc(EKEEP*4);
    int*     sorted = (int*)    alloc(EKEEP*4);
    int*     seg    = (int*)    alloc(EKEEP*4);
    int*     teg    = (int*)    alloc(EKEEP*4);
    float*   bvec   = (float*)  alloc(EKEEP*4);
    float*   bqc    = (float*)  alloc(1536*4);
    float*   bvc    = (float*)  alloc(1536*4);
    float*   kb     = (float*)  alloc(1536*4);
    float*   bvo    = (float*)  alloc(1536*4);
    ushortT* MpT    = (ushortT*)alloc(1536L*1536*2);   // Mp^T, [n][k]
    ushortT* WvoT   = (ushortT*)alloc(1536L*1536*2);   // Wvo^T, [n][k]
    const size_t fixedB = off;

    // union region: phase-W (Wqc|Wkc, Wvc reuses Wqc) vs chunk scratch
    char* uni = ws + off;
    ushortT* Wqc = (ushortT*)uni;
    ushortT* Wkc = (ushortT*)(uni + ((1536L*1536*2 + 255) & ~255L));
    ushortT* Wvc = Wqc;

    const size_t perG = 64L*512*2 + 2L*64*256*2 + 2L*256*1536*2 + 256L*256*4; // 1.97MB
    int G = 128;
    while (G > 1 && fixedB + (size_t)G*perG + 8192 > ws_size) G >>= 1;

    size_t coff = fixedB;
    auto calloc2 = [&](size_t bytes) {
        void* p = ws + coff;
        coff = (coff + bytes + 255) & ~(size_t)255;
        return p;
    };
    ushortT* h_c  = (ushortT*)calloc2((size_t)G*64*512*2);
    ushortT* h1_c = (ushortT*)calloc2((size_t)G*64*256*2);
    ushortT* ag_c = (ushortT*)calloc2((size_t)G*64*256*2);
    ushortT* F_c  = (ushortT*)calloc2((size_t)G*256*1536*2);
    ushortT* T_c  = (ushortT*)calloc2((size_t)G*256*1536*2);
    float*   S_c  = (float*)  calloc2((size_t)G*256*256*4);

    const float scale = 0.02551551815399144f;  // 1/sqrt(1536)
    const dim3 blk(256);

    detect_k<<<1, blk, 0, stream>>>((const unsigned int*)x, dflag);
    sort_k<<<128, blk, 0, stream>>>(edges, sorted, seg, teg);

    // ---- phase W: weight precombination ----
    gemm_k<ushortT,false,false,false,false,false><<<dim3(24,24,1), blk, 0, stream>>>(
        qkvW, C_RT, 0, inWq, C_RT, 0, (const void*)nullptr, C_BF, 0, 0,
        Wqc, dflag, 1536, 4608, 1536, 1536, 0,0,0, 1.f);
    gemm_k<ushortT,false,false,false,false,false><<<dim3(24,24,1), blk, 0, stream>>>(
        qkvW, C_RT, 1536, inWk, C_RT, 0, (const void*)nullptr, C_BF, 0, 0,
        Wkc, dflag, 1536, 4608, 1536, 1536, 0,0,0, 1.f);
    colcomb_k<<<6, blk, 0, stream>>>(qkvb, C_RT, 0, inWq, C_RT, inbq, C_RT, bqc, dflag);
    // MpT = scale * Wkc @ Wqc^T   (Mp^T directly — operands swapped)
    gemm_k<ushortT,true,false,false,false,false><<<dim3(24,24,1), blk, 0, stream>>>(
        Wkc, C_BF, 0, Wqc, C_BF, 0, (const void*)nullptr, C_BF, 0, 0,
        MpT, dflag, 1536, 1536, 1536, 1536, 0,0,0, scale);
    // kb = scale * Wkc @ bqc
    rowdot_k<<<1536, blk, 0, stream>>>(Wkc, bqc, kb, scale);
    // Wvc = qkvW[:,3072:4608] @ inWv  (reuses Wqc slot)
    gemm_k<ushortT,false,false,false,false,false><<<dim3(24,24,1), blk, 0, stream>>>(
        qkvW, C_RT, 3072, inWv, C_RT, 0, (const void*)nullptr, C_BF, 0, 0,
        Wvc, dflag, 1536, 4608, 1536, 1536, 0,0,0, 1.f);
    colcomb_k<<<6, blk, 0, stream>>>(qkvb, C_RT, 3072, inWv, C_RT, inbv, C_RT, bvc, dflag);
    // WvoT = (Wvc @ outW)^T  via transposed store
    gemm_k<ushortT,false,false,false,false,true><<<dim3(24,24,1), blk, 0, stream>>>(
        Wvc, C_BF, 0, outW, C_RT, 0, (const void*)nullptr, C_BF, 0, 0,
        WvoT, dflag, 1536, 1536, 1536, 1536, 0,0,0, 1.f);
    colcomb_k<<<6, blk, 0, stream>>>(bvc, C_F32, 0, outW, C_RT, outb, C_RT, bvo, dflag);

    // ---- per-chunk pipeline ----
    const int nchunk = 128 / G;
    const int EC = G * 256;
    for (int c = 0; c < nchunk; ++c) {
        const int b0 = c * G;
        gconv1_k<<<G, blk, 0, stream>>>(b0, x, edges, ea, wembW, wembB,
                                        g1Wrel, g1brel, g1Wroot, h1_c, dflag);
        gconv2_agg_k<<<G, blk, 0, stream>>>(b0, h1_c, edges, ea, wembW, wembB, ag_c, dflag);
        gemm_k<ushortT,false,true,false,false,false><<<dim3(8,G,1), blk, 0, stream>>>(
            ag_c, C_BF, 0, g2Wrel, C_RT, 0, g2brel, C_RT, 0, 0, h_c, dflag,
            256, 256, 512, 512, 0,0,0, 1.f);
        gemm_k<ushortT,false,false,true,true,false><<<dim3(8,G,1), blk, 0, stream>>>(
            h1_c, C_BF, 0, g2Wroot, C_RT, 0, (const void*)nullptr, C_BF, 0, 0, h_c, dflag,
            256, 256, 512, 512, 0,0,0, 1.f);
        gnorm_k<<<G, blk, 0, stream>>>(h_c, gnw, gnb, gnms, dflag);
        fbuild_k<<<EC, blk, 0, stream>>>(b0, G*64-1, h_c, sorted, seg, teg, ea,
                                         eembW, eembB, kb, F_c, bvec, dflag);
        // T = F @ MpT^T   (fast bf16 path)
        bgemm_k<ushortT,false,false><<<dim3(12, EC/128, 1), blk, 0, stream>>>(
            F_c, MpT, nullptr, T_c, 1536, 1536, 1536, 1536, 0,0,0, 0,0, 1.f);
        // S_b = T_b @ F_b^T + bvec
        bgemm_k<float,true,false><<<dim3(2, 2, G), blk, 0, stream>>>(
            T_c, F_c, bvec + (long)b0*256, S_c, 1536, 1536, 1536, 256,
            256L*1536, 256L*1536, 65536L, 0, 256, 1.f);
        softmax_k<<<EC, blk, 0, stream>>>(S_c);
        // R_b = P_b @ F_b  -> T_c (generic path: A is f32)
        gemm_k<ushortT,false,false,false,false,false><<<dim3(24,4,G), blk, 0, stream>>>(
            S_c, C_F32, 0, F_c, C_BF, 0, (const void*)nullptr, C_BF, 0, 0, T_c, dflag,
            256, 256, 1536, 1536, 65536L, 256L*1536, 256L*1536, 1.f);
        // F += R @ WvoT^T + bvo   (fast bf16 path, residual)
        bgemm_k<ushortT,true,true><<<dim3(12, EC/128, 1), blk, 0, stream>>>(
            T_c, WvoT, bvo, F_c, 1536, 1536, 1536, 1536, 0,0,0, 0,0, 1.f);
        ln_head_k<<<EC, blk, 0, stream>>>(b0, F_c, lng, lnb, headW, headb, gout, dflag);
    }

    final_k<<<128, dim3(128), 0, stream>>>(gout, seg, teg, sorted, ea, (float*)d_out, dflag);
}